// Round 8
// baseline (269.513 us; speedup 1.0000x reference)
//
#include <hip/hip_runtime.h>
#include <hip/hip_bf16.h>

#define ALPHA 0.2f
constexpr int N = 2048;
constexpr int NW = N / 64;     // 32 mask words per row

typedef __attribute__((ext_vector_type(8))) short short8v;  // bf16 bits x8
typedef __attribute__((ext_vector_type(4))) float f32x4;

__device__ inline unsigned short bf16_rne(float f) {
  unsigned u = __float_as_uint(f);
  return (unsigned short)((u + 0x7fffu + ((u >> 16) & 1u)) >> 16);
}

struct GParams {
  const float* nf; const int* adj;
  const float *encW1, *encb1, *encW2, *encb2;
  const float *gatW0, *gata0, *gatW1, *gata1, *gatW2, *gata2;
  const float *clsW1, *clsb1, *clsW2, *clsb2;
  unsigned long long* mask;
  unsigned short *wt0hi, *wt0lo, *wt1hi, *wt1lo;
  unsigned short *x0hi, *x0lo;
  unsigned short* hT;
  float *s1, *s2, *pm1, *pm1h3;
  unsigned short *xAhi, *xAlo;
  float *xB, *h2, *emb, *eprob;
  unsigned* bar;
};

// ---- device-scope grid barrier: READ-spin (no RMW polling) ----
// bar[0] = arrival count, bar[32] = generation (separate cache lines)
__device__ inline void gsync(unsigned* bar) {
  __syncthreads();
  if (threadIdx.x == 0) {
    __threadfence();  // publish this block's writes
    unsigned gen = __hip_atomic_load(&bar[32], __ATOMIC_RELAXED, __HIP_MEMORY_SCOPE_AGENT);
    unsigned old = __hip_atomic_fetch_add(&bar[0], 1u, __ATOMIC_RELAXED, __HIP_MEMORY_SCOPE_AGENT);
    if (old == gridDim.x - 1) {
      __hip_atomic_store(&bar[0], 0u, __ATOMIC_RELAXED, __HIP_MEMORY_SCOPE_AGENT);
      __threadfence();
      __hip_atomic_fetch_add(&bar[32], 1u, __ATOMIC_RELEASE, __HIP_MEMORY_SCOPE_AGENT);
    } else {
      while (__hip_atomic_load(&bar[32], __ATOMIC_RELAXED, __HIP_MEMORY_SCOPE_AGENT) == gen)
        __builtin_amdgcn_s_sleep(2);
    }
    __threadfence();  // acquire side
  }
  __syncthreads();
}

// ---------------- phase: pack adj + W transpose/split + encoder ----------------
__device__ void phase_prep(const GParams& P) {
  const int t = threadIdx.x, b = blockIdx.x;
  {  // pack adjacency: 4096 waves x 16 words
    int gwave = b * 8 + (t >> 6), lane = t & 63;
#pragma unroll
    for (int i = 0; i < 16; i++) {
      int word = gwave * 16 + i;
      unsigned long long m = __ballot(P.adj[(size_t)word * 64 + lane] != 0);
      if (lane == 0) P.mask[word] = m;
    }
  }
  {  // W0/W1 transpose + hi/lo split
    int gtid = b * 512 + t;
    if (gtid < 16384) {
      int head = gtid >> 12, idx = gtid & 4095;
      int o = idx >> 6, k = idx & 63;
      float v = P.gatW0[(head * 64 + k) * 64 + o];
      unsigned short hb = bf16_rne(v);
      P.wt0hi[gtid] = hb;
      P.wt0lo[gtid] = bf16_rne(v - __uint_as_float((unsigned)hb << 16));
    }
    if (gtid < 65536) {
      int head = gtid >> 14, idx = gtid & 16383;
      int o = idx >> 8, k = idx & 255;
      float v = P.gatW1[((size_t)head * 256 + k) * 64 + o];
      unsigned short hb = bf16_rne(v);
      size_t oi = ((size_t)head * 64 + o) * 256 + k;
      P.wt1hi[oi] = hb;
      P.wt1lo[oi] = bf16_rne(v - __uint_as_float((unsigned)hb << 16));
    }
  }
  if (b < 256) {  // encoder MLP, 8 nodes/block (two 4-node halves)
    __shared__ float nfs[2][4][10], x1e[2][4][64], pred[2][4][4][64];
    const int half = t >> 8, tl = t & 255;
    const int j = tl >> 6, o = tl & 63;
    const int n0 = b * 8 + half * 4;
    if (tl < 40) nfs[half][tl / 10][tl % 10] = P.nf[n0 * 10 + tl];
    __syncthreads();
    float acc = P.encb1[o];
#pragma unroll
    for (int k = 0; k < 10; k++) acc = fmaf(nfs[half][j][k], P.encW1[k * 64 + o], acc);
    x1e[half][j][o] = fmaxf(acc, 0.f);
    __syncthreads();
    {
      const int kq = j;
      float pp0 = 0, pp1 = 0, pp2 = 0, pp3 = 0;
#pragma unroll
      for (int kk = 0; kk < 16; kk++) {
        int k = kq * 16 + kk;
        float wv = P.encW2[k * 64 + o];
        pp0 = fmaf(x1e[half][0][k], wv, pp0);
        pp1 = fmaf(x1e[half][1][k], wv, pp1);
        pp2 = fmaf(x1e[half][2][k], wv, pp2);
        pp3 = fmaf(x1e[half][3][k], wv, pp3);
      }
      pred[half][kq][0][o] = pp0; pred[half][kq][1][o] = pp1;
      pred[half][kq][2][o] = pp2; pred[half][kq][3][o] = pp3;
    }
    __syncthreads();
    float v = P.encb2[o] + pred[half][0][j][o] + pred[half][1][j][o] +
              pred[half][2][j][o] + pred[half][3][j][o];
    unsigned short hb = bf16_rne(v);
    P.x0hi[(n0 + j) * 64 + o] = hb;
    P.x0lo[(n0 + j) * 64 + o] = bf16_rne(v - __uint_as_float((unsigned)hb << 16));
  }
}

// ---------------- phase: MFMA projection (blocks 0..255, 2 units/block) ----------------
template <int K>
__device__ void phase_proj(const GParams& P, const unsigned short* xhi, const unsigned short* xlo,
                           const unsigned short* wthi, const unsigned short* wtlo,
                           const float* avec) {
  __shared__ float s1p[2][4][16], s2p[2][4][16];
  const int b = blockIdx.x;
  if (b < 256) {
    const int wave = threadIdx.x >> 6, lane = threadIdx.x & 63;
    const int sub = wave >> 2, wl = wave & 3;
    const int unit = b * 2 + sub;
    const int head = unit & 3, ntile = unit >> 2;
    const int n0 = ntile * 16;
    const int il = lane & 15, kgrp = lane >> 4;
    const int o0 = wl * 16;
    const unsigned short* __restrict__ Ah = wthi + ((size_t)head * 64 + o0 + il) * K;
    const unsigned short* __restrict__ Al = wtlo + ((size_t)head * 64 + o0 + il) * K;
    const unsigned short* __restrict__ Bh = xhi + (size_t)(n0 + il) * K;
    const unsigned short* __restrict__ Bl = xlo + (size_t)(n0 + il) * K;
    f32x4 acc = {0, 0, 0, 0};
#pragma unroll
    for (int ks = 0; ks < K / 32; ks++) {
      const int ka = ks * 32 + kgrp * 8;
      short8v ah = *(const short8v*)(Ah + ka);
      short8v al = *(const short8v*)(Al + ka);
      short8v bh = *(const short8v*)(Bh + ka);
      short8v bl = *(const short8v*)(Bl + ka);
      acc = __builtin_amdgcn_mfma_f32_16x16x32_bf16(ah, bh, acc, 0, 0, 0);
      acc = __builtin_amdgcn_mfma_f32_16x16x32_bf16(al, bh, acc, 0, 0, 0);
      acc = __builtin_amdgcn_mfma_f32_16x16x32_bf16(ah, bl, acc, 0, 0, 0);
    }
    const int n = n0 + il;
    float p1 = 0.f, p2 = 0.f;
#pragma unroll
    for (int r = 0; r < 4; r++) {
      const int o = o0 + kgrp * 4 + r;
      P.hT[((size_t)head * 64 + o) * N + n] = bf16_rne(acc[r]);
      p1 = fmaf(acc[r], avec[head * 128 + o], p1);
      p2 = fmaf(acc[r], avec[head * 128 + 64 + o], p2);
    }
    p1 += __shfl_xor(p1, 16); p1 += __shfl_xor(p1, 32);
    p2 += __shfl_xor(p2, 16); p2 += __shfl_xor(p2, 32);
    if (kgrp == 0) { s1p[sub][wl][il] = p1; s2p[sub][wl][il] = p2; }
    __syncthreads();
    if (threadIdx.x < 32) {
      int sub2 = threadIdx.x >> 4, il2 = threadIdx.x & 15;
      int unit2 = b * 2 + sub2, head2 = unit2 & 3, ntile2 = unit2 >> 2;
      int nn = ntile2 * 16 + il2;
      float v1 = s1p[sub2][0][il2] + s1p[sub2][1][il2] + s1p[sub2][2][il2] + s1p[sub2][3][il2];
      float v2 = s2p[sub2][0][il2] + s2p[sub2][1][il2] + s2p[sub2][2][il2] + s2p[sub2][3][il2];
      P.s1[head2 * N + nn] = v1;
      P.s2[head2 * N + nn] = v2;
      float m1 = v1;
#pragma unroll
      for (int s = 1; s < 16; s <<= 1) m1 = fmaxf(m1, __shfl_xor(m1, s));
      if (il2 == 0) P.pm1[head2 * 128 + ntile2] = m1;
    }
  }
}

// ---------------- phase: fused MFMA aggregation (all 512 blocks) ----------------
__device__ void phase_agg(const GParams& P, float* xoutf,
                          unsigned short* xohi, unsigned short* xolo) {
  __shared__ float red[8][16][65];
  __shared__ float wred[8][16];
  const int b = blockIdx.x;
  const int head = b & 3, p0 = (b >> 2) * 16;
  const int wave = threadIdx.x >> 6, lane = threadIdx.x & 63;
  const int col = lane & 15, kgrp = lane >> 4;
  const int p = p0 + col;
  const float s2pv = P.s2[head * N + p];
  float sm = fmaxf(P.pm1[head * 128 + lane], P.pm1[head * 128 + 64 + lane]);
#pragma unroll
  for (int s = 1; s < 64; s <<= 1) sm = fmaxf(sm, __shfl_xor(sm, s));
  const float mraw = sm + s2pv;
  const float mp = fmaxf(mraw, ALPHA * mraw);
  const float* __restrict__ s1h = P.s1 + head * N;
  const int qbase = wave * 256;
  const unsigned long long* __restrict__ mr = P.mask + (size_t)p * NW + (qbase >> 6);
  unsigned long long mw0 = mr[0], mw1 = mr[1], mw2 = mr[2], mw3 = mr[3];
  const unsigned short* __restrict__ hTu = P.hT;
  size_t boff[4];
#pragma unroll
  for (int ff = 0; ff < 4; ff++) boff[ff] = ((size_t)head * 64 + ff * 16 + col) * N;

  f32x4 acc[4] = {{0,0,0,0},{0,0,0,0},{0,0,0,0},{0,0,0,0}};
  float wsum = 0.f;
#pragma unroll
  for (int ks = 0; ks < 8; ks++) {
    const int qa = qbase + ks * 32 + kgrp * 8;
    float4 s1v0 = *(const float4*)(s1h + qa);
    float4 s1v1 = *(const float4*)(s1h + qa + 4);
    unsigned long long mwsel = (ks < 2) ? mw0 : (ks < 4) ? mw1 : (ks < 6) ? mw2 : mw3;
    unsigned b8 = (unsigned)((mwsel >> ((ks & 1) * 32 + kgrp * 8)) & 0xFFull);
    float sv[8] = {s1v0.x, s1v0.y, s1v0.z, s1v0.w, s1v1.x, s1v1.y, s1v1.z, s1v1.w};
    short8v a_hi, a_lo;
#pragma unroll
    for (int e = 0; e < 8; e++) {
      float ev = sv[e] + s2pv;
      float lr = fmaxf(ev, ALPHA * ev);
      float w = ((b8 >> e) & 1u) ? __expf(lr - mp) : 0.f;
      wsum += w;
      unsigned short hb = bf16_rne(w);
      float hf = __uint_as_float((unsigned)hb << 16);
      a_hi[e] = (short)hb;
      a_lo[e] = (short)bf16_rne(w - hf);
    }
#pragma unroll
    for (int ff = 0; ff < 4; ff++) {
      short8v b_hi = *(const short8v*)(hTu + boff[ff] + qa);
      acc[ff] = __builtin_amdgcn_mfma_f32_16x16x32_bf16(a_hi, b_hi, acc[ff], 0, 0, 0);
      acc[ff] = __builtin_amdgcn_mfma_f32_16x16x32_bf16(a_lo, b_hi, acc[ff], 0, 0, 0);
    }
  }
  wsum += __shfl_xor(wsum, 16);
  wsum += __shfl_xor(wsum, 32);
#pragma unroll
  for (int ff = 0; ff < 4; ff++)
#pragma unroll
    for (int r = 0; r < 4; r++)
      red[wave][kgrp * 4 + r][ff * 16 + col] = acc[ff][r];
  if (lane < 16) wred[wave][lane] = wsum;
  __syncthreads();
#pragma unroll
  for (int rep = 0; rep < 2; rep++) {
    int idx = threadIdx.x + rep * 512;
    int pl = idx >> 6, f = idx & 63;
    float num = 0.f, dn = 0.f;
#pragma unroll
    for (int w = 0; w < 8; w++) { num += red[w][pl][f]; dn += wred[w][pl]; }
    float v = num / dn;
    v = v > 0.f ? v : (__expf(v) - 1.f);
    size_t oi = (size_t)(p0 + pl) * 256 + head * 64 + f;
    if (xoutf) xoutf[oi] = v;
    if (xohi) {
      unsigned short hb = bf16_rne(v);
      float hf = __uint_as_float((unsigned)hb << 16);
      xohi[oi] = hb;
      xolo[oi] = bf16_rne(v - hf);
    }
  }
  __syncthreads();
}

// ---------------- phase: layer-2 projection (blocks 0..255, 8 nodes/block) ----------------
__device__ void phase_h3(const GParams& P) {
  __shared__ float xr[8][256];
  const int b = blockIdx.x, t = threadIdx.x;
  if (b < 256) {
    const int n0 = b * 8;
#pragma unroll
    for (int i = 0; i < 4; i++) {
      int idx = t + i * 512;
      xr[idx >> 8][idx & 255] = P.xB[(size_t)n0 * 256 + idx];
    }
    __syncthreads();
    const int half = t >> 8, tl = t & 255;
    const int head = tl >> 6, o = tl & 63;
    const float* __restrict__ Wh = P.gatW2 + (size_t)head * 256 * 3;
    const float* __restrict__ av = P.gata2 + head * 6;
    float m1 = -3.4e38f;
#pragma unroll
    for (int jj = 0; jj < 4; jj++) {
      float a0 = 0.f, a1 = 0.f, a2 = 0.f;
#pragma unroll
      for (int i = 0; i < 4; i++) {
        int k = o + 64 * i;
        float xv = xr[half * 4 + jj][k];
        a0 = fmaf(xv, Wh[k * 3 + 0], a0);
        a1 = fmaf(xv, Wh[k * 3 + 1], a1);
        a2 = fmaf(xv, Wh[k * 3 + 2], a2);
      }
      for (int s = 32; s; s >>= 1) {
        a0 += __shfl_xor(a0, s); a1 += __shfl_xor(a1, s); a2 += __shfl_xor(a2, s);
      }
      float p1 = a0 * av[0] + a1 * av[1] + a2 * av[2];
      float p2 = a0 * av[3] + a1 * av[4] + a2 * av[5];
      m1 = fmaxf(m1, p1);
      if (o == 0) {
        int nn = n0 + half * 4 + jj;
        float* hq = P.h2 + ((size_t)head * N + nn) * 3;
        hq[0] = a0; hq[1] = a1; hq[2] = a2;
        P.s1[head * N + nn] = p1;
        P.s2[head * N + nn] = p2;
      }
    }
    if (o == 0) P.pm1h3[head * 512 + b * 2 + half] = m1;
  }
}

// ---------------- phase: layer-2 aggregation + head-mean + ELU -> emb ----------------
__device__ void phase_agg2(const GParams& P) {
  __shared__ float red2[2][4][4];
  const int b = blockIdx.x, t = threadIdx.x;
  const int sub = t >> 8, tl = t & 255;
  const int head = tl >> 6, lane = tl & 63;
#pragma unroll
  for (int pass = 0; pass < 2; pass++) {
    const int p = b * 4 + pass * 2 + sub;
    const float s2pv = P.s2[head * N + p];
    float sm = -3.4e38f;
#pragma unroll
    for (int i = 0; i < 8; i++) sm = fmaxf(sm, P.pm1h3[head * 512 + lane + i * 64]);
#pragma unroll
    for (int s = 1; s < 64; s <<= 1) sm = fmaxf(sm, __shfl_xor(sm, s));
    float mraw = sm + s2pv;
    const float mhv = fmaxf(mraw, ALPHA * mraw);
    const float* __restrict__ s1h = P.s1 + head * N;
    float a0 = 0.f, a1 = 0.f, a2 = 0.f, wsum = 0.f;
#pragma unroll 2
    for (int i = 0; i < 32; i++) {
      unsigned long long mwd = P.mask[(size_t)p * NW + i];
      int q = i * 64 + lane;
      if ((mwd >> lane) & 1ull) {
        float e = s1h[q] + s2pv;
        e = fmaxf(e, ALPHA * e);
        float w = __expf(e - mhv);
        const float* __restrict__ hq = P.h2 + ((size_t)head * N + q) * 3;
        a0 = fmaf(w, hq[0], a0);
        a1 = fmaf(w, hq[1], a1);
        a2 = fmaf(w, hq[2], a2);
        wsum += w;
      }
    }
    for (int s = 32; s; s >>= 1) {
      a0 += __shfl_xor(a0, s); a1 += __shfl_xor(a1, s);
      a2 += __shfl_xor(a2, s); wsum += __shfl_xor(wsum, s);
    }
    if (lane == 0) { red2[sub][head][0] = a0; red2[sub][head][1] = a1;
                     red2[sub][head][2] = a2; red2[sub][head][3] = wsum; }
    __syncthreads();
    if (tl < 3) {
      float v = 0.f;
#pragma unroll
      for (int hh = 0; hh < 4; hh++) v += red2[sub][hh][tl] / red2[sub][hh][3];
      v *= 0.25f;
      v = v > 0.f ? v : (__expf(v) - 1.f);
      P.emb[p * 3 + tl] = v;
    }
    __syncthreads();
  }
}

// ---------------- phase: all-pairs edge classifier (all 512 blocks) ----------------
// block b: q = (b&3)*512 + t, p-rows [ (b>>2)*16, +16 ) in two 8-row passes
__device__ void phase_cls(const GParams& P) {
  const int b = blockIdx.x, t = threadIdx.x;
  const int q = (b & 3) * 512 + t;
  const int p0 = (b >> 2) * 16;
  __shared__ float ep[16][3];
  __shared__ float w1s[96], b1s[32], w2s[32];
  __shared__ float b2s_;
  if (t < 96) w1s[t] = P.clsW1[t];
  else if (t < 128) b1s[t - 96] = P.clsb1[t - 96];
  else if (t < 160) w2s[t - 128] = P.clsW2[t - 128];
  else if (t == 160) b2s_ = P.clsb2[0];
  else if (t >= 192 && t < 240) ((float*)ep)[t - 192] = P.emb[p0 * 3 + t - 192];
  __syncthreads();
  float e0 = P.emb[q * 3 + 0], e1 = P.emb[q * 3 + 1], e2 = P.emb[q * 3 + 2];
#pragma unroll
  for (int pass = 0; pass < 2; pass++) {
    float d[8][3];
#pragma unroll
    for (int i = 0; i < 8; i++) {
      d[i][0] = fabsf(ep[pass * 8 + i][0] - e0);
      d[i][1] = fabsf(ep[pass * 8 + i][1] - e1);
      d[i][2] = fabsf(ep[pass * 8 + i][2] - e2);
    }
    float acc[8] = {0, 0, 0, 0, 0, 0, 0, 0};
#pragma unroll
    for (int j = 0; j < 32; j++) {
      float c0 = w1s[j], c1 = w1s[32 + j], c2 = w1s[64 + j], bb = b1s[j], w2 = w2s[j];
#pragma unroll
      for (int i = 0; i < 8; i++) {
        float hv = fmaxf(bb + d[i][0] * c0 + d[i][1] * c1 + d[i][2] * c2, 0.f);
        acc[i] += hv * w2;
      }
    }
#pragma unroll
    for (int i = 0; i < 8; i++) {
      float x = acc[i] + b2s_;
      P.eprob[(size_t)(p0 + pass * 8 + i) * N + q] = 1.f / (1.f + __expf(-x));
    }
  }
}

// ---------------- single fused pipeline kernel ----------------
__global__ void __launch_bounds__(512, 4) mega_kernel(GParams P) {
  phase_prep(P);
  gsync(P.bar);
  phase_proj<64>(P, P.x0hi, P.x0lo, P.wt0hi, P.wt0lo, P.gata0);
  gsync(P.bar);
  phase_agg(P, nullptr, P.xAhi, P.xAlo);
  gsync(P.bar);
  phase_proj<256>(P, P.xAhi, P.xAlo, P.wt1hi, P.wt1lo, P.gata1);
  gsync(P.bar);
  phase_agg(P, P.xB, nullptr, nullptr);
  gsync(P.bar);
  phase_h3(P);
  gsync(P.bar);
  phase_agg2(P);
  gsync(P.bar);
  phase_cls(P);
}

extern "C" void kernel_launch(void* const* d_in, const int* in_sizes, int n_in,
                              void* d_out, int out_size, void* d_ws, size_t ws_size,
                              hipStream_t stream) {
  float* ws = (float*)d_ws;
  unsigned short* hT   = (unsigned short*)ws;              // 262144 f
  float* s1   = ws + 262144;                               // 8192
  float* s2   = s1 + 8192;                                 // 8192
  float* pm1  = s2 + 8192;                                 // 512
  float* pm1h3= pm1 + 512;                                 // 2048
  unsigned short* x0hi = (unsigned short*)(pm1h3 + 2048);  // 65536 f
  unsigned short* x0lo = x0hi + 131072;                    // 65536 f
  unsigned short* wt0hi= x0lo + 131072;                    // 8192 f
  unsigned short* wt0lo= wt0hi + 16384;                    // 8192 f
  unsigned short* wt1hi= wt0lo + 16384;                    // 32768 f
  unsigned short* wt1lo= wt1hi + 65536;                    // 32768 f
  unsigned short* xAhi = wt1lo + 65536;                    // 262144 f
  unsigned short* xAlo = xAhi + 524288;                    // 262144 f
  float* xB   = (float*)(xAlo + 524288);                   // 524288 f
  float* h2   = xB + 524288;                               // 24576 f
  unsigned long long* mask = (unsigned long long*)(h2 + 24576); // 131072 f
  unsigned* bar = (unsigned*)(mask + 65536);               // 64 uints

  float* emb = (float*)d_out;
  float* eprob = emb + N * 3;

  hipMemsetAsync(bar, 0, 256, stream);

  GParams P;
  P.nf = (const float*)d_in[0];   P.adj = (const int*)d_in[1];
  P.encW1 = (const float*)d_in[2]; P.encb1 = (const float*)d_in[3];
  P.encW2 = (const float*)d_in[4]; P.encb2 = (const float*)d_in[5];
  P.gatW0 = (const float*)d_in[6]; P.gata0 = (const float*)d_in[7];
  P.gatW1 = (const float*)d_in[8]; P.gata1 = (const float*)d_in[9];
  P.gatW2 = (const float*)d_in[10]; P.gata2 = (const float*)d_in[11];
  P.clsW1 = (const float*)d_in[12]; P.clsb1 = (const float*)d_in[13];
  P.clsW2 = (const float*)d_in[14]; P.clsb2 = (const float*)d_in[15];
  P.mask = mask;
  P.wt0hi = wt0hi; P.wt0lo = wt0lo; P.wt1hi = wt1hi; P.wt1lo = wt1lo;
  P.x0hi = x0hi; P.x0lo = x0lo;
  P.hT = hT; P.s1 = s1; P.s2 = s2; P.pm1 = pm1; P.pm1h3 = pm1h3;
  P.xAhi = xAhi; P.xAlo = xAlo; P.xB = xB; P.h2 = h2; P.emb = emb;
  P.eprob = eprob;
  P.bar = bar;

  mega_kernel<<<dim3(512), dim3(512), 0, stream>>>(P);
}

// Round 9
// 118.302 us; speedup vs baseline: 2.2782x; 2.2782x over previous
//
#include <hip/hip_runtime.h>
#include <hip/hip_bf16.h>

#define ALPHA 0.2f
constexpr int N = 2048;
constexpr int NW = N / 64;     // 32 mask words per row

typedef __attribute__((ext_vector_type(8))) short short8v;  // bf16 bits x8
typedef __attribute__((ext_vector_type(4))) float f32x4;

__device__ inline unsigned short bf16_rne(float f) {
  unsigned u = __float_as_uint(f);
  return (unsigned short)((u + 0x7fffu + ((u >> 16) & 1u)) >> 16);
}

// ---------------- prep: pack adj + W transpose/split + encoder (one dispatch) ----------------
__global__ void __launch_bounds__(512) prep_kernel(
    const float* __restrict__ nf, const int* __restrict__ adj,
    const float* __restrict__ encW1, const float* __restrict__ encb1,
    const float* __restrict__ encW2, const float* __restrict__ encb2,
    const float* __restrict__ gatW0, const float* __restrict__ gatW1,
    unsigned long long* __restrict__ mask,
    unsigned short* __restrict__ wt0hi, unsigned short* __restrict__ wt0lo,
    unsigned short* __restrict__ wt1hi, unsigned short* __restrict__ wt1lo,
    unsigned short* __restrict__ x0hi, unsigned short* __restrict__ x0lo) {
  const int t = threadIdx.x, b = blockIdx.x;
  {  // pack adjacency: 512 blocks x 8 waves x 16 words
    int gwave = b * 8 + (t >> 6), lane = t & 63;
#pragma unroll
    for (int i = 0; i < 16; i++) {
      int word = gwave * 16 + i;
      unsigned long long m = __ballot(adj[(size_t)word * 64 + lane] != 0);
      if (lane == 0) mask[word] = m;
    }
  }
  {  // W0/W1 transpose + hi/lo split
    int gtid = b * 512 + t;
    if (gtid < 16384) {
      int head = gtid >> 12, idx = gtid & 4095;
      int o = idx >> 6, k = idx & 63;
      float v = gatW0[(head * 64 + k) * 64 + o];
      unsigned short hb = bf16_rne(v);
      wt0hi[gtid] = hb;
      wt0lo[gtid] = bf16_rne(v - __uint_as_float((unsigned)hb << 16));
    }
    if (gtid < 65536) {
      int head = gtid >> 14, idx = gtid & 16383;
      int o = idx >> 8, k = idx & 255;
      float v = gatW1[((size_t)head * 256 + k) * 64 + o];
      unsigned short hb = bf16_rne(v);
      size_t oi = ((size_t)head * 64 + o) * 256 + k;
      wt1hi[oi] = hb;
      wt1lo[oi] = bf16_rne(v - __uint_as_float((unsigned)hb << 16));
    }
  }
  if (b < 256) {  // encoder MLP, 8 nodes/block (two 4-node halves)
    __shared__ float nfs[2][4][10], x1e[2][4][64], pred[2][4][4][64];
    const int half = t >> 8, tl = t & 255;
    const int j = tl >> 6, o = tl & 63;
    const int n0 = b * 8 + half * 4;
    if (tl < 40) nfs[half][tl / 10][tl % 10] = nf[n0 * 10 + tl];
    __syncthreads();
    float acc = encb1[o];
#pragma unroll
    for (int k = 0; k < 10; k++) acc = fmaf(nfs[half][j][k], encW1[k * 64 + o], acc);
    x1e[half][j][o] = fmaxf(acc, 0.f);
    __syncthreads();
    {
      const int kq = j;
      float pp0 = 0, pp1 = 0, pp2 = 0, pp3 = 0;
#pragma unroll
      for (int kk = 0; kk < 16; kk++) {
        int k = kq * 16 + kk;
        float wv = encW2[k * 64 + o];
        pp0 = fmaf(x1e[half][0][k], wv, pp0);
        pp1 = fmaf(x1e[half][1][k], wv, pp1);
        pp2 = fmaf(x1e[half][2][k], wv, pp2);
        pp3 = fmaf(x1e[half][3][k], wv, pp3);
      }
      pred[half][kq][0][o] = pp0; pred[half][kq][1][o] = pp1;
      pred[half][kq][2][o] = pp2; pred[half][kq][3][o] = pp3;
    }
    __syncthreads();
    float v = encb2[o] + pred[half][0][j][o] + pred[half][1][j][o] +
              pred[half][2][j][o] + pred[half][3][j][o];
    unsigned short hb = bf16_rne(v);
    x0hi[(n0 + j) * 64 + o] = hb;
    x0lo[(n0 + j) * 64 + o] = bf16_rne(v - __uint_as_float((unsigned)hb << 16));
  }
}

// ---------------- MFMA projection: hT[head][o][n] = (x @ W)^T, + s1/s2 + per-tile s1 max ----------------
// grid (N/16 = 128, H), block 256 = 4 waves; wave = o-strip of 16. 3-term hi/lo MFMA.
template <int K>
__global__ void __launch_bounds__(256, 4)
proj_mfma_kernel(const unsigned short* __restrict__ xhi, const unsigned short* __restrict__ xlo,
                 const unsigned short* __restrict__ wthi, const unsigned short* __restrict__ wtlo,
                 const float* __restrict__ avec,
                 unsigned short* __restrict__ hT, float* __restrict__ s1, float* __restrict__ s2,
                 float* __restrict__ pm1) {
  const int head = blockIdx.y;
  const int n0 = blockIdx.x * 16;
  const int wave = threadIdx.x >> 6, lane = threadIdx.x & 63;
  const int il = lane & 15, kgrp = lane >> 4;
  const int o0 = wave * 16;
  const unsigned short* __restrict__ Ah = wthi + ((size_t)head * 64 + o0 + il) * K;
  const unsigned short* __restrict__ Al = wtlo + ((size_t)head * 64 + o0 + il) * K;
  const unsigned short* __restrict__ Bh = xhi + (size_t)(n0 + il) * K;
  const unsigned short* __restrict__ Bl = xlo + (size_t)(n0 + il) * K;
  f32x4 acc = {0, 0, 0, 0};
#pragma unroll
  for (int ks = 0; ks < K / 32; ks++) {
    const int ka = ks * 32 + kgrp * 8;
    short8v ah = *(const short8v*)(Ah + ka);
    short8v al = *(const short8v*)(Al + ka);
    short8v bh = *(const short8v*)(Bh + ka);
    short8v bl = *(const short8v*)(Bl + ka);
    acc = __builtin_amdgcn_mfma_f32_16x16x32_bf16(ah, bh, acc, 0, 0, 0);
    acc = __builtin_amdgcn_mfma_f32_16x16x32_bf16(al, bh, acc, 0, 0, 0);
    acc = __builtin_amdgcn_mfma_f32_16x16x32_bf16(ah, bl, acc, 0, 0, 0);
  }
  const int n = n0 + il;
  float p1 = 0.f, p2 = 0.f;
#pragma unroll
  for (int r = 0; r < 4; r++) {
    const int o = o0 + kgrp * 4 + r;
    hT[((size_t)head * 64 + o) * N + n] = bf16_rne(acc[r]);
    p1 = fmaf(acc[r], avec[head * 128 + o], p1);
    p2 = fmaf(acc[r], avec[head * 128 + 64 + o], p2);
  }
  p1 += __shfl_xor(p1, 16); p1 += __shfl_xor(p1, 32);
  p2 += __shfl_xor(p2, 16); p2 += __shfl_xor(p2, 32);
  __shared__ float s1p[4][16], s2p[4][16];
  if (kgrp == 0) { s1p[wave][il] = p1; s2p[wave][il] = p2; }
  __syncthreads();
  if (threadIdx.x < 16) {
    int nn = n0 + threadIdx.x;
    float v1 = s1p[0][threadIdx.x] + s1p[1][threadIdx.x] + s1p[2][threadIdx.x] + s1p[3][threadIdx.x];
    float v2 = s2p[0][threadIdx.x] + s2p[1][threadIdx.x] + s2p[2][threadIdx.x] + s2p[3][threadIdx.x];
    s1[head * N + nn] = v1;
    s2[head * N + nn] = v2;
    float m1 = v1;
#pragma unroll
    for (int s = 1; s < 16; s <<= 1) m1 = fmaxf(m1, __shfl_xor(m1, s));
    if (threadIdx.x == 0) pm1[head * 128 + blockIdx.x] = m1;
  }
}

// ---------------- fused MFMA aggregation + denom + normalize + ELU + concat ----------------
// grid (N/16, H), block 1024 = 16 waves; wave w = K-chunk of 128 q (8 waves/SIMD for latency hiding).
template <bool WF32, bool WBF>
__global__ void __launch_bounds__(1024, 8)
agg_fused_kernel(const unsigned short* __restrict__ hTu,
                 const float* __restrict__ s1, const float* __restrict__ s2,
                 const float* __restrict__ pm1,
                 const unsigned long long* __restrict__ mask,
                 float* __restrict__ xout,
                 unsigned short* __restrict__ xohi, unsigned short* __restrict__ xolo) {
  const int head = blockIdx.y;
  const int p0 = blockIdx.x * 16;
  const int wave = threadIdx.x >> 6, lane = threadIdx.x & 63;
  const int col = lane & 15, kgrp = lane >> 4;
  const int p = p0 + col;
  const float s2pv = s2[head * N + p];
  float sm = fmaxf(pm1[head * 128 + lane], pm1[head * 128 + 64 + lane]);
#pragma unroll
  for (int s = 1; s < 64; s <<= 1) sm = fmaxf(sm, __shfl_xor(sm, s));
  const float mraw = sm + s2pv;
  const float mp = fmaxf(mraw, ALPHA * mraw);
  const float* __restrict__ s1h = s1 + head * N;
  const int qbase = wave * 128;
  const unsigned long long* __restrict__ mr = mask + (size_t)p * NW + (qbase >> 6);
  unsigned long long mw0 = mr[0], mw1 = mr[1];
  size_t boff[4];
#pragma unroll
  for (int ff = 0; ff < 4; ff++) boff[ff] = ((size_t)head * 64 + ff * 16 + col) * N;

  f32x4 acc[4] = {{0,0,0,0},{0,0,0,0},{0,0,0,0},{0,0,0,0}};
  float wsum = 0.f;
#pragma unroll
  for (int ks = 0; ks < 4; ks++) {
    const int qa = qbase + ks * 32 + kgrp * 8;
    float4 s1v0 = *(const float4*)(s1h + qa);
    float4 s1v1 = *(const float4*)(s1h + qa + 4);
    unsigned long long mwsel = (ks < 2) ? mw0 : mw1;
    unsigned b8 = (unsigned)((mwsel >> ((ks & 1) * 32 + kgrp * 8)) & 0xFFull);
    float sv[8] = {s1v0.x, s1v0.y, s1v0.z, s1v0.w, s1v1.x, s1v1.y, s1v1.z, s1v1.w};
    short8v a_hi, a_lo;
#pragma unroll
    for (int e = 0; e < 8; e++) {
      float ev = sv[e] + s2pv;
      float lr = fmaxf(ev, ALPHA * ev);
      float w = ((b8 >> e) & 1u) ? __expf(lr - mp) : 0.f;
      wsum += w;
      unsigned short hb = bf16_rne(w);
      float hf = __uint_as_float((unsigned)hb << 16);
      a_hi[e] = (short)hb;
      a_lo[e] = (short)bf16_rne(w - hf);
    }
#pragma unroll
    for (int ff = 0; ff < 4; ff++) {
      short8v b_hi = *(const short8v*)(hTu + boff[ff] + qa);
      acc[ff] = __builtin_amdgcn_mfma_f32_16x16x32_bf16(a_hi, b_hi, acc[ff], 0, 0, 0);
      acc[ff] = __builtin_amdgcn_mfma_f32_16x16x32_bf16(a_lo, b_hi, acc[ff], 0, 0, 0);
    }
  }
  wsum += __shfl_xor(wsum, 16);
  wsum += __shfl_xor(wsum, 32);

  // two-stage cross-wave reduction (16 waves -> 8 partials -> epilogue)
  __shared__ float red[8][16][65];
  __shared__ float wred[8][16];
  if (wave >= 8) {
#pragma unroll
    for (int ff = 0; ff < 4; ff++)
#pragma unroll
      for (int r = 0; r < 4; r++)
        red[wave - 8][kgrp * 4 + r][ff * 16 + col] = acc[ff][r];
    if (lane < 16) wred[wave - 8][lane] = wsum;
  }
  __syncthreads();
  if (wave < 8) {
#pragma unroll
    for (int ff = 0; ff < 4; ff++)
#pragma unroll
      for (int r = 0; r < 4; r++)
        red[wave][kgrp * 4 + r][ff * 16 + col] += acc[ff][r];
    if (lane < 16) wred[wave][lane] += wsum;
  }
  __syncthreads();
  {  // epilogue: 1024 threads = 16 p x 64 f
    int pl = threadIdx.x >> 6, f = threadIdx.x & 63;
    float num = 0.f, dn = 0.f;
#pragma unroll
    for (int w = 0; w < 8; w++) { num += red[w][pl][f]; dn += wred[w][pl]; }
    float v = num / dn;
    v = v > 0.f ? v : (__expf(v) - 1.f);
    size_t oi = (size_t)(p0 + pl) * 256 + head * 64 + f;
    if (WF32) xout[oi] = v;
    if (WBF) {
      unsigned short hb = bf16_rne(v);
      float hf = __uint_as_float((unsigned)hb << 16);
      xohi[oi] = hb;
      xolo[oi] = bf16_rne(v - hf);
    }
  }
}

// ---------------- layer-2 projection (F_out=3), 4 nodes/block, per-tile s1 max ----------------
__global__ void h3_kernel(const float* __restrict__ x, const float* __restrict__ W,
                          const float* __restrict__ a, float* __restrict__ h2,
                          float* __restrict__ s1, float* __restrict__ s2,
                          float* __restrict__ pm1h3) {
  const int n0 = blockIdx.x * 4;
  const int head = threadIdx.x >> 6, o = threadIdx.x & 63;
  __shared__ float xr[4][256];
  for (int k = threadIdx.x; k < 1024; k += 256) xr[k >> 8][k & 255] = x[(size_t)n0 * 256 + k];
  __syncthreads();
  const float* __restrict__ Wh = W + (size_t)head * 256 * 3;
  float m1 = -3.4e38f;
#pragma unroll
  for (int jj = 0; jj < 4; jj++) {
    float a0 = 0.f, a1 = 0.f, a2 = 0.f;
#pragma unroll
    for (int i = 0; i < 4; i++) {
      int k = o + 64 * i;
      float xv = xr[jj][k];
      a0 = fmaf(xv, Wh[k * 3 + 0], a0);
      a1 = fmaf(xv, Wh[k * 3 + 1], a1);
      a2 = fmaf(xv, Wh[k * 3 + 2], a2);
    }
    for (int s = 32; s; s >>= 1) {
      a0 += __shfl_xor(a0, s); a1 += __shfl_xor(a1, s); a2 += __shfl_xor(a2, s);
    }
    float p1 = a0 * a[head * 6 + 0] + a1 * a[head * 6 + 1] + a2 * a[head * 6 + 2];
    float p2 = a0 * a[head * 6 + 3] + a1 * a[head * 6 + 4] + a2 * a[head * 6 + 5];
    m1 = fmaxf(m1, p1);
    if (o == 0) {
      float* hq = h2 + ((size_t)head * N + n0 + jj) * 3;
      hq[0] = a0; hq[1] = a1; hq[2] = a2;
      s1[head * N + n0 + jj] = p1;
      s2[head * N + n0 + jj] = p2;
    }
  }
  if (o == 0) pm1h3[head * 512 + blockIdx.x] = m1;
}

// ---------------- layer-2 aggregation, self-normalizing, fused head-mean + ELU -> emb ----------------
__global__ void agg2_kernel(const float* __restrict__ h2, const float* __restrict__ s1,
                            const float* __restrict__ s2, const float* __restrict__ pm1h3,
                            const unsigned long long* __restrict__ mask,
                            float* __restrict__ emb) {
  const int p = blockIdx.x;
  const int head = threadIdx.x >> 6, lane = threadIdx.x & 63;
  const float s2pv = s2[head * N + p];
  float sm = -3.4e38f;
  for (int i = lane; i < 512; i += 64) sm = fmaxf(sm, pm1h3[head * 512 + i]);
#pragma unroll
  for (int s = 1; s < 64; s <<= 1) sm = fmaxf(sm, __shfl_xor(sm, s));
  float mraw = sm + s2pv;
  const float mhv = fmaxf(mraw, ALPHA * mraw);
  const float* __restrict__ s1h = s1 + head * N;
  float a0 = 0.f, a1 = 0.f, a2 = 0.f, wsum = 0.f;
#pragma unroll 2
  for (int i = 0; i < 32; i++) {
    unsigned long long mwd = mask[(size_t)p * NW + i];
    int q = i * 64 + lane;
    if ((mwd >> lane) & 1ull) {
      float e = s1h[q] + s2pv;
      e = fmaxf(e, ALPHA * e);
      float w = __expf(e - mhv);
      const float* __restrict__ hq = h2 + ((size_t)head * N + q) * 3;
      a0 = fmaf(w, hq[0], a0);
      a1 = fmaf(w, hq[1], a1);
      a2 = fmaf(w, hq[2], a2);
      wsum += w;
    }
  }
  for (int s = 32; s; s >>= 1) {
    a0 += __shfl_xor(a0, s); a1 += __shfl_xor(a1, s);
    a2 += __shfl_xor(a2, s); wsum += __shfl_xor(wsum, s);
  }
  __shared__ float red[4][4];
  if (lane == 0) { red[head][0] = a0; red[head][1] = a1; red[head][2] = a2; red[head][3] = wsum; }
  __syncthreads();
  if (threadIdx.x < 3) {
    int f = threadIdx.x;
    float v = 0.f;
#pragma unroll
    for (int hh = 0; hh < 4; hh++) v += red[hh][f] / red[hh][3];
    v *= 0.25f;
    v = v > 0.f ? v : (__expf(v) - 1.f);
    emb[p * 3 + f] = v;
  }
}

// ---------------- all-pairs edge classifier ----------------
__global__ void cls_kernel(const float* __restrict__ emb,
                           const float* __restrict__ W1, const float* __restrict__ b1,
                           const float* __restrict__ W2, const float* __restrict__ b2,
                           float* __restrict__ out) {
  int q = blockIdx.x * 256 + threadIdx.x;
  int p0 = blockIdx.y * 8;
  __shared__ float ep[8][3];
  __shared__ float w1s[96], b1s[32], w2s[32];
  __shared__ float b2s;
  int t = threadIdx.x;
  if (t < 96) w1s[t] = W1[t];
  else if (t < 128) b1s[t - 96] = b1[t - 96];
  else if (t < 160) w2s[t - 128] = W2[t - 128];
  else if (t == 160) b2s = b2[0];
  else if (t >= 192 && t < 216) ((float*)ep)[t - 192] = emb[p0 * 3 + t - 192];
  __syncthreads();
  float e0 = emb[q * 3 + 0], e1 = emb[q * 3 + 1], e2 = emb[q * 3 + 2];
  float d[8][3];
#pragma unroll
  for (int i = 0; i < 8; i++) {
    d[i][0] = fabsf(ep[i][0] - e0);
    d[i][1] = fabsf(ep[i][1] - e1);
    d[i][2] = fabsf(ep[i][2] - e2);
  }
  float acc[8] = {0, 0, 0, 0, 0, 0, 0, 0};
#pragma unroll
  for (int j = 0; j < 32; j++) {
    float c0 = w1s[j], c1 = w1s[32 + j], c2 = w1s[64 + j], bb = b1s[j], w2 = w2s[j];
#pragma unroll
    for (int i = 0; i < 8; i++) {
      float hv = fmaxf(bb + d[i][0] * c0 + d[i][1] * c1 + d[i][2] * c2, 0.f);
      acc[i] += hv * w2;
    }
  }
#pragma unroll
  for (int i = 0; i < 8; i++) {
    float x = acc[i] + b2s;
    out[(size_t)(p0 + i) * N + q] = 1.f / (1.f + __expf(-x));
  }
}

extern "C" void kernel_launch(void* const* d_in, const int* in_sizes, int n_in,
                              void* d_out, int out_size, void* d_ws, size_t ws_size,
                              hipStream_t stream) {
  const float* nf    = (const float*)d_in[0];
  const int*   adj   = (const int*)d_in[1];
  const float* encW1 = (const float*)d_in[2];
  const float* encb1 = (const float*)d_in[3];
  const float* encW2 = (const float*)d_in[4];
  const float* encb2 = (const float*)d_in[5];
  const float* gatW0 = (const float*)d_in[6];
  const float* gata0 = (const float*)d_in[7];
  const float* gatW1 = (const float*)d_in[8];
  const float* gata1 = (const float*)d_in[9];
  const float* gatW2 = (const float*)d_in[10];
  const float* gata2 = (const float*)d_in[11];
  const float* clsW1 = (const float*)d_in[12];
  const float* clsb1 = (const float*)d_in[13];
  const float* clsW2 = (const float*)d_in[14];
  const float* clsb2 = (const float*)d_in[15];

  float* ws = (float*)d_ws;
  unsigned short* hT   = (unsigned short*)ws;              // 262144 f
  float* s1   = ws + 262144;                               // 8192
  float* s2   = s1 + 8192;                                 // 8192
  float* pm1  = s2 + 8192;                                 // 512
  float* pm1h3= pm1 + 512;                                 // 2048
  unsigned short* x0hi = (unsigned short*)(pm1h3 + 2048);  // 65536 f
  unsigned short* x0lo = x0hi + 131072;                    // 65536 f
  unsigned short* wt0hi= x0lo + 131072;                    // 8192 f
  unsigned short* wt0lo= wt0hi + 16384;                    // 8192 f
  unsigned short* wt1hi= wt0lo + 16384;                    // 32768 f
  unsigned short* wt1lo= wt1hi + 65536;                    // 32768 f
  unsigned short* xAhi = wt1lo + 65536;                    // 262144 f
  unsigned short* xAlo = xAhi + 524288;                    // 262144 f
  float* xB   = (float*)(xAlo + 524288);                   // 524288 f
  float* h2   = xB + 524288;                               // 24576 f
  unsigned long long* mask = (unsigned long long*)(h2 + 24576); // 131072 f

  float* emb = (float*)d_out;
  float* eprob = emb + N * 3;

  prep_kernel<<<dim3(512), dim3(512), 0, stream>>>(
      nf, adj, encW1, encb1, encW2, encb2, gatW0, gatW1,
      mask, wt0hi, wt0lo, wt1hi, wt1lo, x0hi, x0lo);

  // ---- GAT layer 0 ----
  proj_mfma_kernel<64><<<dim3(N / 16, 4), dim3(256), 0, stream>>>(
      x0hi, x0lo, wt0hi, wt0lo, gata0, hT, s1, s2, pm1);
  agg_fused_kernel<false, true><<<dim3(N / 16, 4), dim3(1024), 0, stream>>>(
      hT, s1, s2, pm1, mask, nullptr, xAhi, xAlo);

  // ---- GAT layer 1 ----
  proj_mfma_kernel<256><<<dim3(N / 16, 4), dim3(256), 0, stream>>>(
      xAhi, xAlo, wt1hi, wt1lo, gata1, hT, s1, s2, pm1);
  agg_fused_kernel<true, false><<<dim3(N / 16, 4), dim3(1024), 0, stream>>>(
      hT, s1, s2, pm1, mask, xB, nullptr, nullptr);

  // ---- GAT layer 2 ----
  h3_kernel<<<dim3(N / 4), dim3(256), 0, stream>>>(xB, gatW2, gata2, h2, s1, s2, pm1h3);
  agg2_kernel<<<dim3(N), dim3(256), 0, stream>>>(h2, s1, s2, pm1h3, mask, emb);

  // ---- classifier ----
  cls_kernel<<<dim3(8, N / 8), dim3(256), 0, stream>>>(emb, clsW1, clsb1, clsW2, clsb2, eprob);
}

// Round 11
// 109.838 us; speedup vs baseline: 2.4537x; 1.0771x over previous
//
#include <hip/hip_runtime.h>
#include <hip/hip_bf16.h>
#include <hip/hip_fp16.h>

#define ALPHA 0.2f
#define LOG2E 1.44269504088896340736f
constexpr int N = 2048;
constexpr int NW = N / 64;     // 32 mask words per row

typedef __attribute__((ext_vector_type(8))) short short8v;  // bf16 bits x8
typedef __attribute__((ext_vector_type(4))) float f32x4;

__device__ inline unsigned short bf16_rne(float f) {
  unsigned u = __float_as_uint(f);
  return (unsigned short)((u + 0x7fffu + ((u >> 16) & 1u)) >> 16);
}

// packed fp16 ReLU via v_pk_max_f16 (avoids __hmax2 fp16/bf16 overload ambiguity)
__device__ inline __half2 relu_h2(__half2 a) {
  unsigned ua = *(unsigned*)&a, ur;
  asm("v_pk_max_f16 %0, %1, 0" : "=v"(ur) : "v"(ua));
  return *(__half2*)&ur;
}

// ---------------- prep: pack adj + W transpose/split + encoder (one dispatch) ----------------
__global__ void __launch_bounds__(512) prep_kernel(
    const float* __restrict__ nf, const int* __restrict__ adj,
    const float* __restrict__ encW1, const float* __restrict__ encb1,
    const float* __restrict__ encW2, const float* __restrict__ encb2,
    const float* __restrict__ gatW0, const float* __restrict__ gatW1,
    unsigned long long* __restrict__ mask,
    unsigned short* __restrict__ wt0hi, unsigned short* __restrict__ wt0lo,
    unsigned short* __restrict__ wt1hi, unsigned short* __restrict__ wt1lo,
    unsigned short* __restrict__ x0hi, unsigned short* __restrict__ x0lo) {
  const int t = threadIdx.x, b = blockIdx.x;
  {  // pack adjacency: 512 blocks x 8 waves x 16 words
    int gwave = b * 8 + (t >> 6), lane = t & 63;
#pragma unroll
    for (int i = 0; i < 16; i++) {
      int word = gwave * 16 + i;
      unsigned long long m = __ballot(adj[(size_t)word * 64 + lane] != 0);
      if (lane == 0) mask[word] = m;
    }
  }
  {  // W0/W1 transpose + hi/lo split
    int gtid = b * 512 + t;
    if (gtid < 16384) {
      int head = gtid >> 12, idx = gtid & 4095;
      int o = idx >> 6, k = idx & 63;
      float v = gatW0[(head * 64 + k) * 64 + o];
      unsigned short hb = bf16_rne(v);
      wt0hi[gtid] = hb;
      wt0lo[gtid] = bf16_rne(v - __uint_as_float((unsigned)hb << 16));
    }
    if (gtid < 65536) {
      int head = gtid >> 14, idx = gtid & 16383;
      int o = idx >> 8, k = idx & 255;
      float v = gatW1[((size_t)head * 256 + k) * 64 + o];
      unsigned short hb = bf16_rne(v);
      size_t oi = ((size_t)head * 64 + o) * 256 + k;
      wt1hi[oi] = hb;
      wt1lo[oi] = bf16_rne(v - __uint_as_float((unsigned)hb << 16));
    }
  }
  if (b < 256) {  // encoder MLP, 8 nodes/block (two 4-node halves)
    __shared__ float nfs[2][4][10], x1e[2][4][64], pred[2][4][4][64];
    const int half = t >> 8, tl = t & 255;
    const int j = tl >> 6, o = tl & 63;
    const int n0 = b * 8 + half * 4;
    if (tl < 40) nfs[half][tl / 10][tl % 10] = nf[n0 * 10 + tl];
    __syncthreads();
    float acc = encb1[o];
#pragma unroll
    for (int k = 0; k < 10; k++) acc = fmaf(nfs[half][j][k], encW1[k * 64 + o], acc);
    x1e[half][j][o] = fmaxf(acc, 0.f);
    __syncthreads();
    {
      const int kq = j;
      float pp0 = 0, pp1 = 0, pp2 = 0, pp3 = 0;
#pragma unroll
      for (int kk = 0; kk < 16; kk++) {
        int k = kq * 16 + kk;
        float wv = encW2[k * 64 + o];
        pp0 = fmaf(x1e[half][0][k], wv, pp0);
        pp1 = fmaf(x1e[half][1][k], wv, pp1);
        pp2 = fmaf(x1e[half][2][k], wv, pp2);
        pp3 = fmaf(x1e[half][3][k], wv, pp3);
      }
      pred[half][kq][0][o] = pp0; pred[half][kq][1][o] = pp1;
      pred[half][kq][2][o] = pp2; pred[half][kq][3][o] = pp3;
    }
    __syncthreads();
    float v = encb2[o] + pred[half][0][j][o] + pred[half][1][j][o] +
              pred[half][2][j][o] + pred[half][3][j][o];
    unsigned short hb = bf16_rne(v);
    x0hi[(n0 + j) * 64 + o] = hb;
    x0lo[(n0 + j) * 64 + o] = bf16_rne(v - __uint_as_float((unsigned)hb << 16));
  }
}

// ---------------- MFMA projection: hT[head][o][n] = (x @ W)^T, + s1/s2 (log2e-scaled) ----------------
// grid (N/16 = 128, H), block 256 = 4 waves; wave = o-strip of 16. 3-term hi/lo MFMA.
template <int K>
__global__ void __launch_bounds__(256, 4)
proj_mfma_kernel(const unsigned short* __restrict__ xhi, const unsigned short* __restrict__ xlo,
                 const unsigned short* __restrict__ wthi, const unsigned short* __restrict__ wtlo,
                 const float* __restrict__ avec,
                 unsigned short* __restrict__ hT, float* __restrict__ s1, float* __restrict__ s2,
                 float* __restrict__ pm1) {
  const int head = blockIdx.y;
  const int n0 = blockIdx.x * 16;
  const int wave = threadIdx.x >> 6, lane = threadIdx.x & 63;
  const int il = lane & 15, kgrp = lane >> 4;
  const int o0 = wave * 16;
  const unsigned short* __restrict__ Ah = wthi + ((size_t)head * 64 + o0 + il) * K;
  const unsigned short* __restrict__ Al = wtlo + ((size_t)head * 64 + o0 + il) * K;
  const unsigned short* __restrict__ Bh = xhi + (size_t)(n0 + il) * K;
  const unsigned short* __restrict__ Bl = xlo + (size_t)(n0 + il) * K;
  f32x4 acc = {0, 0, 0, 0};
#pragma unroll
  for (int ks = 0; ks < K / 32; ks++) {
    const int ka = ks * 32 + kgrp * 8;
    short8v ah = *(const short8v*)(Ah + ka);
    short8v al = *(const short8v*)(Al + ka);
    short8v bh = *(const short8v*)(Bh + ka);
    short8v bl = *(const short8v*)(Bl + ka);
    acc = __builtin_amdgcn_mfma_f32_16x16x32_bf16(ah, bh, acc, 0, 0, 0);
    acc = __builtin_amdgcn_mfma_f32_16x16x32_bf16(al, bh, acc, 0, 0, 0);
    acc = __builtin_amdgcn_mfma_f32_16x16x32_bf16(ah, bl, acc, 0, 0, 0);
  }
  const int n = n0 + il;
  float p1 = 0.f, p2 = 0.f;
#pragma unroll
  for (int r = 0; r < 4; r++) {
    const int o = o0 + kgrp * 4 + r;
    hT[((size_t)head * 64 + o) * N + n] = bf16_rne(acc[r]);
    p1 = fmaf(acc[r], avec[head * 128 + o], p1);
    p2 = fmaf(acc[r], avec[head * 128 + 64 + o], p2);
  }
  p1 += __shfl_xor(p1, 16); p1 += __shfl_xor(p1, 32);
  p2 += __shfl_xor(p2, 16); p2 += __shfl_xor(p2, 32);
  __shared__ float s1p[4][16], s2p[4][16];
  if (kgrp == 0) { s1p[wave][il] = p1; s2p[wave][il] = p2; }
  __syncthreads();
  if (threadIdx.x < 16) {
    int nn = n0 + threadIdx.x;
    // log2e scaling: lrelu is positively homogeneous, so scaled s1/s2 let agg use native exp2
    float v1 = (s1p[0][threadIdx.x] + s1p[1][threadIdx.x] + s1p[2][threadIdx.x] + s1p[3][threadIdx.x]) * LOG2E;
    float v2 = (s2p[0][threadIdx.x] + s2p[1][threadIdx.x] + s2p[2][threadIdx.x] + s2p[3][threadIdx.x]) * LOG2E;
    s1[head * N + nn] = v1;
    s2[head * N + nn] = v2;
    float m1 = v1;
#pragma unroll
    for (int s = 1; s < 16; s <<= 1) m1 = fmaxf(m1, __shfl_xor(m1, s));
    if (threadIdx.x == 0) pm1[head * 128 + blockIdx.x] = m1;
  }
}

// ---------------- fused MFMA aggregation + denom + normalize + ELU + concat ----------------
// grid (N/16, H), block 512 = 8 waves; wave w = K-chunk of 256 q. Single-MFMA (a_hi only).
template <bool WF32, bool WBF>
__global__ void __launch_bounds__(512, 4)
agg_fused_kernel(const unsigned short* __restrict__ hTu,
                 const float* __restrict__ s1, const float* __restrict__ s2,
                 const float* __restrict__ pm1,
                 const unsigned long long* __restrict__ mask,
                 float* __restrict__ xout,
                 unsigned short* __restrict__ xohi, unsigned short* __restrict__ xolo) {
  const int head = blockIdx.y;
  const int p0 = blockIdx.x * 16;
  const int wave = threadIdx.x >> 6, lane = threadIdx.x & 63;
  const int col = lane & 15, kgrp = lane >> 4;
  const int p = p0 + col;
  const float s2pv = s2[head * N + p];
  float sm = fmaxf(pm1[head * 128 + lane], pm1[head * 128 + 64 + lane]);
#pragma unroll
  for (int s = 1; s < 64; s <<= 1) sm = fmaxf(sm, __shfl_xor(sm, s));
  const float mraw = sm + s2pv;
  const float mp = fmaxf(mraw, ALPHA * mraw);
  const float* __restrict__ s1h = s1 + head * N;
  const int qbase = wave * 256;
  const unsigned long long* __restrict__ mr = mask + (size_t)p * NW + (qbase >> 6);
  unsigned long long mw0 = mr[0], mw1 = mr[1], mw2 = mr[2], mw3 = mr[3];
  size_t boff[4];
#pragma unroll
  for (int ff = 0; ff < 4; ff++) boff[ff] = ((size_t)head * 64 + ff * 16 + col) * N;

  f32x4 acc[4] = {{0,0,0,0},{0,0,0,0},{0,0,0,0},{0,0,0,0}};
  float wsum = 0.f;
#pragma unroll
  for (int ks = 0; ks < 8; ks++) {
    const int qa = qbase + ks * 32 + kgrp * 8;
    float4 s1v0 = *(const float4*)(s1h + qa);
    float4 s1v1 = *(const float4*)(s1h + qa + 4);
    unsigned long long mwsel = (ks < 2) ? mw0 : (ks < 4) ? mw1 : (ks < 6) ? mw2 : mw3;
    unsigned b8 = (unsigned)((mwsel >> ((ks & 1) * 32 + kgrp * 8)) & 0xFFull);
    float sv[8] = {s1v0.x, s1v0.y, s1v0.z, s1v0.w, s1v1.x, s1v1.y, s1v1.z, s1v1.w};
    short8v a_hi;
#pragma unroll
    for (int e = 0; e < 8; e++) {
      float ev = sv[e] + s2pv;
      float lr = fmaxf(ev, ALPHA * ev);
      float w = ((b8 >> e) & 1u) ? exp2f(lr - mp) : 0.f;  // s1/s2 pre-scaled by log2e
      wsum += w;
      a_hi[e] = (short)bf16_rne(w);
    }
#pragma unroll
    for (int ff = 0; ff < 4; ff++) {
      short8v b_hi = *(const short8v*)(hTu + boff[ff] + qa);
      acc[ff] = __builtin_amdgcn_mfma_f32_16x16x32_bf16(a_hi, b_hi, acc[ff], 0, 0, 0);
    }
  }
  wsum += __shfl_xor(wsum, 16);
  wsum += __shfl_xor(wsum, 32);

  __shared__ float red[8][16][65];
  __shared__ float wred[8][16];
#pragma unroll
  for (int ff = 0; ff < 4; ff++)
#pragma unroll
    for (int r = 0; r < 4; r++)
      red[wave][kgrp * 4 + r][ff * 16 + col] = acc[ff][r];
  if (lane < 16) wred[wave][lane] = wsum;
  __syncthreads();
#pragma unroll
  for (int rep = 0; rep < 2; rep++) {
    int idx = threadIdx.x + rep * 512;
    int pl = idx >> 6, f = idx & 63;
    float num = 0.f, dn = 0.f;
#pragma unroll
    for (int w = 0; w < 8; w++) { num += red[w][pl][f]; dn += wred[w][pl]; }
    float v = num / dn;
    v = v > 0.f ? v : (__expf(v) - 1.f);
    size_t oi = (size_t)(p0 + pl) * 256 + head * 64 + f;
    if (WF32) xout[oi] = v;
    if (WBF) {
      unsigned short hb = bf16_rne(v);
      float hf = __uint_as_float((unsigned)hb << 16);
      xohi[oi] = hb;
      xolo[oi] = bf16_rne(v - hf);
    }
  }
}

// ---------------- layer-2 projection (F_out=3), 4 nodes/block, log2e-scaled s1/s2 ----------------
__global__ void h3_kernel(const float* __restrict__ x, const float* __restrict__ W,
                          const float* __restrict__ a, float* __restrict__ h2,
                          float* __restrict__ s1, float* __restrict__ s2,
                          float* __restrict__ pm1h3) {
  const int n0 = blockIdx.x * 4;
  const int head = threadIdx.x >> 6, o = threadIdx.x & 63;
  __shared__ float xr[4][256];
  for (int k = threadIdx.x; k < 1024; k += 256) xr[k >> 8][k & 255] = x[(size_t)n0 * 256 + k];
  __syncthreads();
  const float* __restrict__ Wh = W + (size_t)head * 256 * 3;
  float m1 = -3.4e38f;
#pragma unroll
  for (int jj = 0; jj < 4; jj++) {
    float a0 = 0.f, a1 = 0.f, a2 = 0.f;
#pragma unroll
    for (int i = 0; i < 4; i++) {
      int k = o + 64 * i;
      float xv = xr[jj][k];
      a0 = fmaf(xv, Wh[k * 3 + 0], a0);
      a1 = fmaf(xv, Wh[k * 3 + 1], a1);
      a2 = fmaf(xv, Wh[k * 3 + 2], a2);
    }
    for (int s = 32; s; s >>= 1) {
      a0 += __shfl_xor(a0, s); a1 += __shfl_xor(a1, s); a2 += __shfl_xor(a2, s);
    }
    float p1 = (a0 * a[head * 6 + 0] + a1 * a[head * 6 + 1] + a2 * a[head * 6 + 2]) * LOG2E;
    float p2 = (a0 * a[head * 6 + 3] + a1 * a[head * 6 + 4] + a2 * a[head * 6 + 5]) * LOG2E;
    m1 = fmaxf(m1, p1);
    if (o == 0) {
      float* hq = h2 + ((size_t)head * N + n0 + jj) * 3;
      hq[0] = a0; hq[1] = a1; hq[2] = a2;
      s1[head * N + n0 + jj] = p1;
      s2[head * N + n0 + jj] = p2;
    }
  }
  if (o == 0) pm1h3[head * 512 + blockIdx.x] = m1;
}

// ---------------- layer-2 aggregation, self-normalizing, fused head-mean + ELU -> emb ----------------
__global__ void agg2_kernel(const float* __restrict__ h2, const float* __restrict__ s1,
                            const float* __restrict__ s2, const float* __restrict__ pm1h3,
                            const unsigned long long* __restrict__ mask,
                            float* __restrict__ emb) {
  const int p = blockIdx.x;
  const int head = threadIdx.x >> 6, lane = threadIdx.x & 63;
  const float s2pv = s2[head * N + p];
  float sm = -3.4e38f;
  for (int i = lane; i < 512; i += 64) sm = fmaxf(sm, pm1h3[head * 512 + i]);
#pragma unroll
  for (int s = 1; s < 64; s <<= 1) sm = fmaxf(sm, __shfl_xor(sm, s));
  float mraw = sm + s2pv;
  const float mhv = fmaxf(mraw, ALPHA * mraw);
  const float* __restrict__ s1h = s1 + head * N;
  float a0 = 0.f, a1 = 0.f, a2 = 0.f, wsum = 0.f;
#pragma unroll 2
  for (int i = 0; i < 32; i++) {
    unsigned long long mwd = mask[(size_t)p * NW + i];
    int q = i * 64 + lane;
    if ((mwd >> lane) & 1ull) {
      float e = s1h[q] + s2pv;
      e = fmaxf(e, ALPHA * e);
      float w = exp2f(e - mhv);
      const float* __restrict__ hq = h2 + ((size_t)head * N + q) * 3;
      a0 = fmaf(w, hq[0], a0);
      a1 = fmaf(w, hq[1], a1);
      a2 = fmaf(w, hq[2], a2);
      wsum += w;
    }
  }
  for (int s = 32; s; s >>= 1) {
    a0 += __shfl_xor(a0, s); a1 += __shfl_xor(a1, s);
    a2 += __shfl_xor(a2, s); wsum += __shfl_xor(wsum, s);
  }
  __shared__ float red[4][4];
  if (lane == 0) { red[head][0] = a0; red[head][1] = a1; red[head][2] = a2; red[head][3] = wsum; }
  __syncthreads();
  if (threadIdx.x < 3) {
    int f = threadIdx.x;
    float v = 0.f;
#pragma unroll
    for (int hh = 0; hh < 4; hh++) v += red[hh][f] / red[hh][3];
    v *= 0.25f;
    v = v > 0.f ? v : (__expf(v) - 1.f);
    emb[p * 3 + f] = v;
  }
}

// ---------------- all-pairs edge classifier (packed fp16 inner) ----------------
__global__ void cls_kernel(const float* __restrict__ emb,
                           const float* __restrict__ W1, const float* __restrict__ b1,
                           const float* __restrict__ W2, const float* __restrict__ b2,
                           float* __restrict__ out) {
  int q = blockIdx.x * 256 + threadIdx.x;
  int p0 = blockIdx.y * 8;
  __shared__ float ep[8][3];
  __shared__ __half2 w1h[96], b1h[32], w2h[32];
  __shared__ float b2s;
  int t = threadIdx.x;
  if (t < 96) w1h[t] = __float2half2_rn(W1[t]);
  else if (t < 128) b1h[t - 96] = __float2half2_rn(b1[t - 96]);
  else if (t < 160) w2h[t - 128] = __float2half2_rn(W2[t - 128]);
  else if (t == 160) b2s = b2[0];
  else if (t >= 192 && t < 216) ((float*)ep)[t - 192] = emb[p0 * 3 + t - 192];
  __syncthreads();
  float e0 = emb[q * 3 + 0], e1 = emb[q * 3 + 1], e2 = emb[q * 3 + 2];
  __half2 d0[4], d1[4], d2[4];
#pragma unroll
  for (int ip = 0; ip < 4; ip++) {
    d0[ip] = __floats2half2_rn(fabsf(ep[2 * ip][0] - e0), fabsf(ep[2 * ip + 1][0] - e0));
    d1[ip] = __floats2half2_rn(fabsf(ep[2 * ip][1] - e1), fabsf(ep[2 * ip + 1][1] - e1));
    d2[ip] = __floats2half2_rn(fabsf(ep[2 * ip][2] - e2), fabsf(ep[2 * ip + 1][2] - e2));
  }
  const __half2 hz = __float2half2_rn(0.f);
  __half2 acc[4] = {hz, hz, hz, hz};
#pragma unroll
  for (int j = 0; j < 32; j++) {
    __half2 c0 = w1h[j], c1 = w1h[32 + j], c2 = w1h[64 + j], bb = b1h[j], w2 = w2h[j];
#pragma unroll
    for (int ip = 0; ip < 4; ip++) {
      __half2 hv = __hfma2(d0[ip], c0, __hfma2(d1[ip], c1, __hfma2(d2[ip], c2, bb)));
      hv = relu_h2(hv);
      acc[ip] = __hfma2(hv, w2, acc[ip]);
    }
  }
#pragma unroll
  for (int ip = 0; ip < 4; ip++) {
    float x0 = __low2float(acc[ip]) + b2s;
    float x1 = __high2float(acc[ip]) + b2s;
    out[(size_t)(p0 + 2 * ip) * N + q] = 1.f / (1.f + __expf(-x0));
    out[(size_t)(p0 + 2 * ip + 1) * N + q] = 1.f / (1.f + __expf(-x1));
  }
}

extern "C" void kernel_launch(void* const* d_in, const int* in_sizes, int n_in,
                              void* d_out, int out_size, void* d_ws, size_t ws_size,
                              hipStream_t stream) {
  const float* nf    = (const float*)d_in[0];
  const int*   adj   = (const int*)d_in[1];
  const float* encW1 = (const float*)d_in[2];
  const float* encb1 = (const float*)d_in[3];
  const float* encW2 = (const float*)d_in[4];
  const float* encb2 = (const float*)d_in[5];
  const float* gatW0 = (const float*)d_in[6];
  const float* gata0 = (const float*)d_in[7];
  const float* gatW1 = (const float*)d_in[8];
  const float* gata1 = (const float*)d_in[9];
  const float* gatW2 = (const float*)d_in[10];
  const float* gata2 = (const float*)d_in[11];
  const float* clsW1 = (const float*)d_in[12];
  const float* clsb1 = (const float*)d_in[13];
  const float* clsW2 = (const float*)d_in[14];
  const float* clsb2 = (const float*)d_in[15];

  float* ws = (float*)d_ws;
  unsigned short* hT   = (unsigned short*)ws;              // 262144 f
  float* s1   = ws + 262144;                               // 8192
  float* s2   = s1 + 8192;                                 // 8192
  float* pm1  = s2 + 8192;                                 // 512
  float* pm1h3= pm1 + 512;                                 // 2048
  unsigned short* x0hi = (unsigned short*)(pm1h3 + 2048);  // 65536 f
  unsigned short* x0lo = x0hi + 131072;                    // 65536 f
  unsigned short* wt0hi= x0lo + 131072;                    // 8192 f
  unsigned short* wt0lo= wt0hi + 16384;                    // 8192 f
  unsigned short* wt1hi= wt0lo + 16384;                    // 32768 f
  unsigned short* wt1lo= wt1hi + 65536;                    // 32768 f
  unsigned short* xAhi = wt1lo + 65536;                    // 262144 f
  unsigned short* xAlo = xAhi + 524288;                    // 262144 f
  float* xB   = (float*)(xAlo + 524288);                   // 524288 f
  float* h2   = xB + 524288;                               // 24576 f
  unsigned long long* mask = (unsigned long long*)(h2 + 24576); // 131072 f

  float* emb = (float*)d_out;
  float* eprob = emb + N * 3;

  prep_kernel<<<dim3(512), dim3(512), 0, stream>>>(
      nf, adj, encW1, encb1, encW2, encb2, gatW0, gatW1,
      mask, wt0hi, wt0lo, wt1hi, wt1lo, x0hi, x0lo);

  // ---- GAT layer 0 ----
  proj_mfma_kernel<64><<<dim3(N / 16, 4), dim3(256), 0, stream>>>(
      x0hi, x0lo, wt0hi, wt0lo, gata0, hT, s1, s2, pm1);
  agg_fused_kernel<false, true><<<dim3(N / 16, 4), dim3(512), 0, stream>>>(
      hT, s1, s2, pm1, mask, nullptr, xAhi, xAlo);

  // ---- GAT layer 1 ----
  proj_mfma_kernel<256><<<dim3(N / 16, 4), dim3(256), 0, stream>>>(
      xAhi, xAlo, wt1hi, wt1lo, gata1, hT, s1, s2, pm1);
  agg_fused_kernel<true, false><<<dim3(N / 16, 4), dim3(512), 0, stream>>>(
      hT, s1, s2, pm1, mask, xB, nullptr, nullptr);

  // ---- GAT layer 2 ----
  h3_kernel<<<dim3(N / 4), dim3(256), 0, stream>>>(xB, gatW2, gata2, h2, s1, s2, pm1h3);
  agg2_kernel<<<dim3(N), dim3(256), 0, stream>>>(h2, s1, s2, pm1h3, mask, emb);

  // ---- classifier ----
  cls_kernel<<<dim3(8, N / 8), dim3(256), 0, stream>>>(emb, clsW1, clsb1, clsW2, clsb2, eprob);
}

// Round 12
// 88.015 us; speedup vs baseline: 3.0621x; 1.2479x over previous
//
#include <hip/hip_runtime.h>
#include <hip/hip_bf16.h>
#include <hip/hip_fp16.h>

#define ALPHA 0.2f
#define LOG2E 1.44269504088896340736f
constexpr int N = 2048;
constexpr int NW = N / 64;     // 32 mask words per row

typedef __attribute__((ext_vector_type(8))) short short8v;  // bf16 bits x8
typedef __attribute__((ext_vector_type(4))) float f32x4;

__device__ inline unsigned short bf16_rne(float f) {
  unsigned u = __float_as_uint(f);
  return (unsigned short)((u + 0x7fffu + ((u >> 16) & 1u)) >> 16);
}

// packed fp16 ReLU via v_pk_max_f16 (avoids __hmax2 fp16/bf16 overload ambiguity)
__device__ inline __half2 relu_h2(__half2 a) {
  unsigned ua = *(unsigned*)&a, ur;
  asm("v_pk_max_f16 %0, %1, 0" : "=v"(ur) : "v"(ua));
  return *(__half2*)&ur;
}

// ---- Fragment-packed layouts (wave-contiguous 1KB chunks; lane = kgrp*16+il) ----
// wtp[head][otile(4)][ks(K/32)][lane(64)][e(8)]   (A of proj: row o = ot*16+il, k = ks*32+(lane>>4)*8+e)
// xp  [ntile(N/16)][ks(K/32)][lane(64)][e(8)]     (B of proj: col n = nt*16+il)
// hTp [head][qchunk(N/32)][ff(4)][lane(64)][e(8)] (B of agg: f = ff*16+(lane&15), q = qc*32+(lane>>4)*8+e)

// ---------------- prep: pack adj + W transpose/split/pack + encoder ----------------
__global__ void __launch_bounds__(512) prep_kernel(
    const float* __restrict__ nf, const int* __restrict__ adj,
    const float* __restrict__ encW1, const float* __restrict__ encb1,
    const float* __restrict__ encW2, const float* __restrict__ encb2,
    const float* __restrict__ gatW0, const float* __restrict__ gatW1,
    unsigned long long* __restrict__ mask,
    unsigned short* __restrict__ wt0hi, unsigned short* __restrict__ wt0lo,
    unsigned short* __restrict__ wt1hi, unsigned short* __restrict__ wt1lo,
    unsigned short* __restrict__ x0hi, unsigned short* __restrict__ x0lo) {
  const int t = threadIdx.x, b = blockIdx.x;
  {  // pack adjacency: 512 blocks x 8 waves x 16 words
    int gwave = b * 8 + (t >> 6), lane = t & 63;
#pragma unroll
    for (int i = 0; i < 16; i++) {
      int word = gwave * 16 + i;
      unsigned long long m = __ballot(adj[(size_t)word * 64 + lane] != 0);
      if (lane == 0) mask[word] = m;
    }
  }
  {  // W0/W1 packed-transpose + hi/lo split
    int gtid = b * 512 + t;
    if (gtid < 16384) {  // W0: K=64 (KS=2)
      int head = gtid >> 12, idx = gtid & 4095;
      int o = idx >> 6, k = idx & 63;
      float v = gatW0[(head * 64 + k) * 64 + o];
      unsigned short hb = bf16_rne(v);
      size_t oi = (((((size_t)head * 4 + (o >> 4)) * 2 + (k >> 5)) * 4 + ((k & 31) >> 3)) * 16 + (o & 15)) * 8 + (k & 7);
      wt0hi[oi] = hb;
      wt0lo[oi] = bf16_rne(v - __uint_as_float((unsigned)hb << 16));
    }
    if (gtid < 65536) {  // W1: K=256 (KS=8)
      int head = gtid >> 14, idx = gtid & 16383;
      int o = idx >> 8, k = idx & 255;
      float v = gatW1[((size_t)head * 256 + k) * 64 + o];
      unsigned short hb = bf16_rne(v);
      size_t oi = (((((size_t)head * 4 + (o >> 4)) * 8 + (k >> 5)) * 4 + ((k & 31) >> 3)) * 16 + (o & 15)) * 8 + (k & 7);
      wt1hi[oi] = hb;
      wt1lo[oi] = bf16_rne(v - __uint_as_float((unsigned)hb << 16));
    }
  }
  if (b < 256) {  // encoder MLP, 8 nodes/block (two 4-node halves)
    __shared__ float nfs[2][4][10], x1e[2][4][64], pred[2][4][4][64];
    const int half = t >> 8, tl = t & 255;
    const int j = tl >> 6, o = tl & 63;
    const int n0 = b * 8 + half * 4;
    if (tl < 40) nfs[half][tl / 10][tl % 10] = nf[n0 * 10 + tl];
    __syncthreads();
    float acc = encb1[o];
#pragma unroll
    for (int k = 0; k < 10; k++) acc = fmaf(nfs[half][j][k], encW1[k * 64 + o], acc);
    x1e[half][j][o] = fmaxf(acc, 0.f);
    __syncthreads();
    {
      const int kq = j;
      float pp0 = 0, pp1 = 0, pp2 = 0, pp3 = 0;
#pragma unroll
      for (int kk = 0; kk < 16; kk++) {
        int k = kq * 16 + kk;
        float wv = encW2[k * 64 + o];
        pp0 = fmaf(x1e[half][0][k], wv, pp0);
        pp1 = fmaf(x1e[half][1][k], wv, pp1);
        pp2 = fmaf(x1e[half][2][k], wv, pp2);
        pp3 = fmaf(x1e[half][3][k], wv, pp3);
      }
      pred[half][kq][0][o] = pp0; pred[half][kq][1][o] = pp1;
      pred[half][kq][2][o] = pp2; pred[half][kq][3][o] = pp3;
    }
    __syncthreads();
    float v = encb2[o] + pred[half][0][j][o] + pred[half][1][j][o] +
              pred[half][2][j][o] + pred[half][3][j][o];
    unsigned short hb = bf16_rne(v);
    const int n = n0 + j;  // node; feature k = o; K=64 -> KS=2
    size_t oi = ((((size_t)(n >> 4) * 2 + (o >> 5)) * 4 + ((o & 31) >> 3)) * 16 + (n & 15)) * 8 + (o & 7);
    x0hi[oi] = hb;
    x0lo[oi] = bf16_rne(v - __uint_as_float((unsigned)hb << 16));
  }
}

// ---------------- MFMA projection (fragment-packed operands) ----------------
// grid (N/16, H), block 256 = 4 waves; wave = o-strip. Writes hTp + s1/s2 (log2e) + pm1.
template <int K>
__global__ void __launch_bounds__(256, 4)
proj_mfma_kernel(const unsigned short* __restrict__ xhi, const unsigned short* __restrict__ xlo,
                 const unsigned short* __restrict__ wthi, const unsigned short* __restrict__ wtlo,
                 const float* __restrict__ avec,
                 unsigned short* __restrict__ hT, float* __restrict__ s1, float* __restrict__ s2,
                 float* __restrict__ pm1) {
  constexpr int KS = K / 32;
  const int head = blockIdx.y;
  const int n0 = blockIdx.x * 16;
  const int wave = threadIdx.x >> 6, lane = threadIdx.x & 63;
  const int il = lane & 15, kgrp = lane >> 4;
  const int o0 = wave * 16;
  const unsigned short* __restrict__ Ah = wthi + ((size_t)(head * 4 + wave) * KS) * 512 + lane * 8;
  const unsigned short* __restrict__ Al = wtlo + ((size_t)(head * 4 + wave) * KS) * 512 + lane * 8;
  const unsigned short* __restrict__ Bh = xhi + ((size_t)blockIdx.x * KS) * 512 + lane * 8;
  const unsigned short* __restrict__ Bl = xlo + ((size_t)blockIdx.x * KS) * 512 + lane * 8;
  f32x4 acc = {0, 0, 0, 0};
#pragma unroll
  for (int ks = 0; ks < KS; ks++) {
    short8v ah = *(const short8v*)(Ah + ks * 512);
    short8v al = *(const short8v*)(Al + ks * 512);
    short8v bh = *(const short8v*)(Bh + ks * 512);
    short8v bl = *(const short8v*)(Bl + ks * 512);
    acc = __builtin_amdgcn_mfma_f32_16x16x32_bf16(ah, bh, acc, 0, 0, 0);
    acc = __builtin_amdgcn_mfma_f32_16x16x32_bf16(al, bh, acc, 0, 0, 0);
    acc = __builtin_amdgcn_mfma_f32_16x16x32_bf16(ah, bl, acc, 0, 0, 0);
  }
  // D: o = o0 + kgrp*4 + r (row), n = n0 + il (col). Write hTp layout.
  const int n = n0 + il;
  const size_t cbase = (((size_t)head * (N / 32) + (n >> 5)) * 4 + wave) * 512;
  const int sub = ((n & 31) >> 3) * 16;  // kgrp_agg*16
  const int eoff = n & 7;
  float p1 = 0.f, p2 = 0.f;
#pragma unroll
  for (int r = 0; r < 4; r++) {
    const int o = o0 + kgrp * 4 + r;
    hT[cbase + (size_t)(sub + kgrp * 4 + r) * 8 + eoff] = bf16_rne(acc[r]);
    p1 = fmaf(acc[r], avec[head * 128 + o], p1);
    p2 = fmaf(acc[r], avec[head * 128 + 64 + o], p2);
  }
  p1 += __shfl_xor(p1, 16); p1 += __shfl_xor(p1, 32);
  p2 += __shfl_xor(p2, 16); p2 += __shfl_xor(p2, 32);
  __shared__ float s1p[4][16], s2p[4][16];
  if (kgrp == 0) { s1p[wave][il] = p1; s2p[wave][il] = p2; }
  __syncthreads();
  if (threadIdx.x < 16) {
    int nn = n0 + threadIdx.x;
    float v1 = (s1p[0][threadIdx.x] + s1p[1][threadIdx.x] + s1p[2][threadIdx.x] + s1p[3][threadIdx.x]) * LOG2E;
    float v2 = (s2p[0][threadIdx.x] + s2p[1][threadIdx.x] + s2p[2][threadIdx.x] + s2p[3][threadIdx.x]) * LOG2E;
    s1[head * N + nn] = v1;
    s2[head * N + nn] = v2;
    float m1 = v1;
#pragma unroll
    for (int s = 1; s < 16; s <<= 1) m1 = fmaxf(m1, __shfl_xor(m1, s));
    if (threadIdx.x == 0) pm1[head * 128 + blockIdx.x] = m1;
  }
}

// ---------------- fused MFMA aggregation + denom + normalize + ELU + concat ----------------
// grid (N/16, H), block 512 = 8 waves; wave w = K-chunk of 256 q. Single-MFMA, packed B.
template <bool WF32, bool WBF>
__global__ void __launch_bounds__(512, 4)
agg_fused_kernel(const unsigned short* __restrict__ hTu,
                 const float* __restrict__ s1, const float* __restrict__ s2,
                 const float* __restrict__ pm1,
                 const unsigned long long* __restrict__ mask,
                 float* __restrict__ xout,
                 unsigned short* __restrict__ xohi, unsigned short* __restrict__ xolo) {
  const int head = blockIdx.y;
  const int p0 = blockIdx.x * 16;
  const int wave = threadIdx.x >> 6, lane = threadIdx.x & 63;
  const int col = lane & 15, kgrp = lane >> 4;
  const int p = p0 + col;
  const float s2pv = s2[head * N + p];
  float sm = fmaxf(pm1[head * 128 + lane], pm1[head * 128 + 64 + lane]);
#pragma unroll
  for (int s = 1; s < 64; s <<= 1) sm = fmaxf(sm, __shfl_xor(sm, s));
  const float mraw = sm + s2pv;
  const float mp = fmaxf(mraw, ALPHA * mraw);
  const float* __restrict__ s1h = s1 + head * N;
  const int qbase = wave * 256;
  const unsigned long long* __restrict__ mr = mask + (size_t)p * NW + (qbase >> 6);
  unsigned long long mw0 = mr[0], mw1 = mr[1], mw2 = mr[2], mw3 = mr[3];
  // packed B: chunk = wave*8 + ks
  const unsigned short* __restrict__ bbase =
      hTu + (((size_t)head * (N / 32) + wave * 8) * 4) * 512 + lane * 8;

  f32x4 acc[4] = {{0,0,0,0},{0,0,0,0},{0,0,0,0},{0,0,0,0}};
  float wsum = 0.f;
#pragma unroll
  for (int ks = 0; ks < 8; ks++) {
    const int qa = qbase + ks * 32 + kgrp * 8;
    float4 s1v0 = *(const float4*)(s1h + qa);
    float4 s1v1 = *(const float4*)(s1h + qa + 4);
    unsigned long long mwsel = (ks < 2) ? mw0 : (ks < 4) ? mw1 : (ks < 6) ? mw2 : mw3;
    unsigned b8 = (unsigned)((mwsel >> ((ks & 1) * 32 + kgrp * 8)) & 0xFFull);
    float sv[8] = {s1v0.x, s1v0.y, s1v0.z, s1v0.w, s1v1.x, s1v1.y, s1v1.z, s1v1.w};
    short8v a_hi;
#pragma unroll
    for (int e = 0; e < 8; e++) {
      float ev = sv[e] + s2pv;
      float lr = fmaxf(ev, ALPHA * ev);
      float w = ((b8 >> e) & 1u) ? exp2f(lr - mp) : 0.f;  // s1/s2 pre-scaled by log2e
      wsum += w;
      a_hi[e] = (short)bf16_rne(w);
    }
#pragma unroll
    for (int ff = 0; ff < 4; ff++) {
      short8v b_hi = *(const short8v*)(bbase + ((size_t)ks * 4 + ff) * 512);
      acc[ff] = __builtin_amdgcn_mfma_f32_16x16x32_bf16(a_hi, b_hi, acc[ff], 0, 0, 0);
    }
  }
  wsum += __shfl_xor(wsum, 16);
  wsum += __shfl_xor(wsum, 32);

  __shared__ float red[8][16][65];
  __shared__ float wred[8][16];
#pragma unroll
  for (int ff = 0; ff < 4; ff++)
#pragma unroll
    for (int r = 0; r < 4; r++)
      red[wave][kgrp * 4 + r][ff * 16 + col] = acc[ff][r];
  if (lane < 16) wred[wave][lane] = wsum;
  __syncthreads();
#pragma unroll
  for (int rep = 0; rep < 2; rep++) {
    int idx = threadIdx.x + rep * 512;
    int pl = idx >> 6, f = idx & 63;
    float num = 0.f, dn = 0.f;
#pragma unroll
    for (int w = 0; w < 8; w++) { num += red[w][pl][f]; dn += wred[w][pl]; }
    float v = num / dn;
    v = v > 0.f ? v : (__expf(v) - 1.f);
    if (WF32) xout[(size_t)(p0 + pl) * 256 + head * 64 + f] = v;
    if (WBF) {
      // xp layout for proj<256>: node nn=p0+pl (tile=blockIdx.x), feature k=head*64+f
      unsigned short hb = bf16_rne(v);
      float hf = __uint_as_float((unsigned)hb << 16);
      size_t oi = ((((size_t)blockIdx.x * 8 + head * 2 + (f >> 5)) * 4 + ((f & 31) >> 3)) * 16 + pl) * 8 + (f & 7);
      xohi[oi] = hb;
      xolo[oi] = bf16_rne(v - hf);
    }
  }
}

// ---------------- layer-2 projection (F_out=3), 4 nodes/block, h2 stride-4 ----------------
__global__ void h3_kernel(const float* __restrict__ x, const float* __restrict__ W,
                          const float* __restrict__ a, float* __restrict__ h2,
                          float* __restrict__ s1, float* __restrict__ s2,
                          float* __restrict__ pm1h3) {
  const int n0 = blockIdx.x * 4;
  const int head = threadIdx.x >> 6, o = threadIdx.x & 63;
  __shared__ float xr[4][256];
  for (int k = threadIdx.x; k < 1024; k += 256) xr[k >> 8][k & 255] = x[(size_t)n0 * 256 + k];
  __syncthreads();
  const float* __restrict__ Wh = W + (size_t)head * 256 * 3;
  float m1 = -3.4e38f;
#pragma unroll
  for (int jj = 0; jj < 4; jj++) {
    float a0 = 0.f, a1 = 0.f, a2 = 0.f;
#pragma unroll
    for (int i = 0; i < 4; i++) {
      int k = o + 64 * i;
      float xv = xr[jj][k];
      a0 = fmaf(xv, Wh[k * 3 + 0], a0);
      a1 = fmaf(xv, Wh[k * 3 + 1], a1);
      a2 = fmaf(xv, Wh[k * 3 + 2], a2);
    }
    for (int s = 32; s; s >>= 1) {
      a0 += __shfl_xor(a0, s); a1 += __shfl_xor(a1, s); a2 += __shfl_xor(a2, s);
    }
    float p1 = (a0 * a[head * 6 + 0] + a1 * a[head * 6 + 1] + a2 * a[head * 6 + 2]) * LOG2E;
    float p2 = (a0 * a[head * 6 + 3] + a1 * a[head * 6 + 4] + a2 * a[head * 6 + 5]) * LOG2E;
    m1 = fmaxf(m1, p1);
    if (o == 0) {
      float* hq = h2 + ((size_t)head * N + n0 + jj) * 4;
      hq[0] = a0; hq[1] = a1; hq[2] = a2; hq[3] = 0.f;
      s1[head * N + n0 + jj] = p1;
      s2[head * N + n0 + jj] = p2;
    }
  }
  if (o == 0) pm1h3[head * 512 + blockIdx.x] = m1;
}

// ---------------- layer-2 aggregation, self-normalizing, fused head-mean + ELU -> emb ----------------
__global__ void agg2_kernel(const float* __restrict__ h2, const float* __restrict__ s1,
                            const float* __restrict__ s2, const float* __restrict__ pm1h3,
                            const unsigned long long* __restrict__ mask,
                            float* __restrict__ emb) {
  const int p = blockIdx.x;
  const int head = threadIdx.x >> 6, lane = threadIdx.x & 63;
  const float s2pv = s2[head * N + p];
  float sm = -3.4e38f;
  for (int i = lane; i < 512; i += 64) sm = fmaxf(sm, pm1h3[head * 512 + i]);
#pragma unroll
  for (int s = 1; s < 64; s <<= 1) sm = fmaxf(sm, __shfl_xor(sm, s));
  float mraw = sm + s2pv;
  const float mhv = fmaxf(mraw, ALPHA * mraw);
  const float* __restrict__ s1h = s1 + head * N;
  float a0 = 0.f, a1 = 0.f, a2 = 0.f, wsum = 0.f;
#pragma unroll 2
  for (int i = 0; i < 32; i++) {
    unsigned long long mwd = mask[(size_t)p * NW + i];
    int q = i * 64 + lane;
    if ((mwd >> lane) & 1ull) {
      float e = s1h[q] + s2pv;
      e = fmaxf(e, ALPHA * e);
      float w = exp2f(e - mhv);
      float4 hv = *(const float4*)(h2 + ((size_t)head * N + q) * 4);
      a0 = fmaf(w, hv.x, a0);
      a1 = fmaf(w, hv.y, a1);
      a2 = fmaf(w, hv.z, a2);
      wsum += w;
    }
  }
  for (int s = 32; s; s >>= 1) {
    a0 += __shfl_xor(a0, s); a1 += __shfl_xor(a1, s);
    a2 += __shfl_xor(a2, s); wsum += __shfl_xor(wsum, s);
  }
  __shared__ float red[4][4];
  if (lane == 0) { red[head][0] = a0; red[head][1] = a1; red[head][2] = a2; red[head][3] = wsum; }
  __syncthreads();
  if (threadIdx.x < 3) {
    int f = threadIdx.x;
    float v = 0.f;
#pragma unroll
    for (int hh = 0; hh < 4; hh++) v += red[hh][f] / red[hh][3];
    v *= 0.25f;
    v = v > 0.f ? v : (__expf(v) - 1.f);
    emb[p * 3 + f] = v;
  }
}

// ---------------- all-pairs edge classifier (packed fp16 inner) ----------------
__global__ void cls_kernel(const float* __restrict__ emb,
                           const float* __restrict__ W1, const float* __restrict__ b1,
                           const float* __restrict__ W2, const float* __restrict__ b2,
                           float* __restrict__ out) {
  int q = blockIdx.x * 256 + threadIdx.x;
  int p0 = blockIdx.y * 8;
  __shared__ float ep[8][3];
  __shared__ __half2 w1h[96], b1h[32], w2h[32];
  __shared__ float b2s;
  int t = threadIdx.x;
  if (t < 96) w1h[t] = __float2half2_rn(W1[t]);
  else if (t < 128) b1h[t - 96] = __float2half2_rn(b1[t - 96]);
  else if (t < 160) w2h[t - 128] = __float2half2_rn(W2[t - 128]);
  else if (t == 160) b2s = b2[0];
  else if (t >= 192 && t < 216) ((float*)ep)[t - 192] = emb[p0 * 3 + t - 192];
  __syncthreads();
  float e0 = emb[q * 3 + 0], e1 = emb[q * 3 + 1], e2 = emb[q * 3 + 2];
  __half2 d0[4], d1[4], d2[4];
#pragma unroll
  for (int ip = 0; ip < 4; ip++) {
    d0[ip] = __floats2half2_rn(fabsf(ep[2 * ip][0] - e0), fabsf(ep[2 * ip + 1][0] - e0));
    d1[ip] = __floats2half2_rn(fabsf(ep[2 * ip][1] - e1), fabsf(ep[2 * ip + 1][1] - e1));
    d2[ip] = __floats2half2_rn(fabsf(ep[2 * ip][2] - e2), fabsf(ep[2 * ip + 1][2] - e2));
  }
  const __half2 hz = __float2half2_rn(0.f);
  __half2 acc[4] = {hz, hz, hz, hz};
#pragma unroll
  for (int j = 0; j < 32; j++) {
    __half2 c0 = w1h[j], c1 = w1h[32 + j], c2 = w1h[64 + j], bb = b1h[j], w2 = w2h[j];
#pragma unroll
    for (int ip = 0; ip < 4; ip++) {
      __half2 hv = __hfma2(d0[ip], c0, __hfma2(d1[ip], c1, __hfma2(d2[ip], c2, bb)));
      hv = relu_h2(hv);
      acc[ip] = __hfma2(hv, w2, acc[ip]);
    }
  }
#pragma unroll
  for (int ip = 0; ip < 4; ip++) {
    float x0 = __low2float(acc[ip]) + b2s;
    float x1 = __high2float(acc[ip]) + b2s;
    out[(size_t)(p0 + 2 * ip) * N + q] = 1.f / (1.f + __expf(-x0));
    out[(size_t)(p0 + 2 * ip + 1) * N + q] = 1.f / (1.f + __expf(-x1));
  }
}

extern "C" void kernel_launch(void* const* d_in, const int* in_sizes, int n_in,
                              void* d_out, int out_size, void* d_ws, size_t ws_size,
                              hipStream_t stream) {
  const float* nf    = (const float*)d_in[0];
  const int*   adj   = (const int*)d_in[1];
  const float* encW1 = (const float*)d_in[2];
  const float* encb1 = (const float*)d_in[3];
  const float* encW2 = (const float*)d_in[4];
  const float* encb2 = (const float*)d_in[5];
  const float* gatW0 = (const float*)d_in[6];
  const float* gata0 = (const float*)d_in[7];
  const float* gatW1 = (const float*)d_in[8];
  const float* gata1 = (const float*)d_in[9];
  const float* gatW2 = (const float*)d_in[10];
  const float* gata2 = (const float*)d_in[11];
  const float* clsW1 = (const float*)d_in[12];
  const float* clsb1 = (const float*)d_in[13];
  const float* clsW2 = (const float*)d_in[14];
  const float* clsb2 = (const float*)d_in[15];

  float* ws = (float*)d_ws;
  unsigned short* hT   = (unsigned short*)ws;              // 524288 sh = 262144 f
  float* s1   = ws + 262144;                               // 8192
  float* s2   = s1 + 8192;                                 // 8192
  float* pm1  = s2 + 8192;                                 // 512
  float* pm1h3= pm1 + 512;                                 // 2048
  unsigned short* x0hi = (unsigned short*)(pm1h3 + 2048);  // 65536 f
  unsigned short* x0lo = x0hi + 131072;                    // 65536 f
  unsigned short* wt0hi= x0lo + 131072;                    // 8192 f
  unsigned short* wt0lo= wt0hi + 16384;                    // 8192 f
  unsigned short* wt1hi= wt0lo + 16384;                    // 32768 f
  unsigned short* wt1lo= wt1hi + 65536;                    // 32768 f
  unsigned short* xAhi = wt1lo + 65536;                    // 262144 f
  unsigned short* xAlo = xAhi + 524288;                    // 262144 f
  float* xB   = (float*)(xAlo + 524288);                   // 524288 f
  float* h2   = xB + 524288;                               // 32768 f (stride-4)
  unsigned long long* mask = (unsigned long long*)(h2 + 32768); // 131072 f

  float* emb = (float*)d_out;
  float* eprob = emb + N * 3;

  prep_kernel<<<dim3(512), dim3(512), 0, stream>>>(
      nf, adj, encW1, encb1, encW2, encb2, gatW0, gatW1,
      mask, wt0hi, wt0lo, wt1hi, wt1lo, x0hi, x0lo);

  // ---- GAT layer 0 ----
  proj_mfma_kernel<64><<<dim3(N / 16, 4), dim3(256), 0, stream>>>(
      x0hi, x0lo, wt0hi, wt0lo, gata0, hT, s1, s2, pm1);
  agg_fused_kernel<false, true><<<dim3(N / 16, 4), dim3(512), 0, stream>>>(
      hT, s1, s2, pm1, mask, nullptr, xAhi, xAlo);

  // ---- GAT layer 1 ----
  proj_mfma_kernel<256><<<dim3(N / 16, 4), dim3(256), 0, stream>>>(
      xAhi, xAlo, wt1hi, wt1lo, gata1, hT, s1, s2, pm1);
  agg_fused_kernel<true, false><<<dim3(N / 16, 4), dim3(512), 0, stream>>>(
      hT, s1, s2, pm1, mask, xB, nullptr, nullptr);

  // ---- GAT layer 2 ----
  h3_kernel<<<dim3(N / 4), dim3(256), 0, stream>>>(xB, gatW2, gata2, h2, s1, s2, pm1h3);
  agg2_kernel<<<dim3(N), dim3(256), 0, stream>>>(h2, s1, s2, pm1h3, mask, emb);

  // ---- classifier ----
  cls_kernel<<<dim3(8, N / 8), dim3(256), 0, stream>>>(emb, clsW1, clsb1, clsW2, clsb2, eprob);
}

// Round 13
// 84.688 us; speedup vs baseline: 3.1824x; 1.0393x over previous
//
#include <hip/hip_runtime.h>
#include <hip/hip_bf16.h>
#include <hip/hip_fp16.h>

#define ALPHA 0.2f
#define LOG2E 1.44269504088896340736f
constexpr int N = 2048;
constexpr int NW = N / 64;     // 32 mask words per row

typedef __attribute__((ext_vector_type(8))) short short8v;  // bf16 bits x8
typedef __attribute__((ext_vector_type(4))) float f32x4;

__device__ inline unsigned short bf16_rne(float f) {
  unsigned u = __float_as_uint(f);
  return (unsigned short)((u + 0x7fffu + ((u >> 16) & 1u)) >> 16);
}

// packed fp16 ReLU via v_pk_max_f16 (avoids __hmax2 fp16/bf16 overload ambiguity)
__device__ inline __half2 relu_h2(__half2 a) {
  unsigned ua = *(unsigned*)&a, ur;
  asm("v_pk_max_f16 %0, %1, 0" : "=v"(ur) : "v"(ua));
  return *(__half2*)&ur;
}

// ---- Fragment-packed layouts (wave-contiguous 1KB chunks; lane = kgrp*16+il) ----
// wtp[head][otile(4)][ks(K/32)][lane(64)][e(8)]   (A of proj: row o = ot*16+il, k = ks*32+(lane>>4)*8+e)
// xp  [ntile(N/16)][ks(K/32)][lane(64)][e(8)]     (B of proj: col n = nt*16+il)
// hTp [head][qchunk(N/32)][ff(4)][lane(64)][e(8)] (B of agg: f = ff*16+(lane&15), q = qc*32+(lane>>4)*8+e)

// ---------------- prep: pack adj + W transpose/split/pack + encoder ----------------
__global__ void __launch_bounds__(512) prep_kernel(
    const float* __restrict__ nf, const int* __restrict__ adj,
    const float* __restrict__ encW1, const float* __restrict__ encb1,
    const float* __restrict__ encW2, const float* __restrict__ encb2,
    const float* __restrict__ gatW0, const float* __restrict__ gatW1,
    unsigned long long* __restrict__ mask,
    unsigned short* __restrict__ wt0hi, unsigned short* __restrict__ wt0lo,
    unsigned short* __restrict__ wt1hi, unsigned short* __restrict__ wt1lo,
    unsigned short* __restrict__ x0hi) {
  const int t = threadIdx.x, b = blockIdx.x;
  {  // pack adjacency: 512 blocks x 8 waves x 16 words
    int gwave = b * 8 + (t >> 6), lane = t & 63;
#pragma unroll
    for (int i = 0; i < 16; i++) {
      int word = gwave * 16 + i;
      unsigned long long m = __ballot(adj[(size_t)word * 64 + lane] != 0);
      if (lane == 0) mask[word] = m;
    }
  }
  {  // W0/W1 packed-transpose + hi/lo split
    int gtid = b * 512 + t;
    if (gtid < 16384) {  // W0: K=64 (KS=2)
      int head = gtid >> 12, idx = gtid & 4095;
      int o = idx >> 6, k = idx & 63;
      float v = gatW0[(head * 64 + k) * 64 + o];
      unsigned short hb = bf16_rne(v);
      size_t oi = (((((size_t)head * 4 + (o >> 4)) * 2 + (k >> 5)) * 4 + ((k & 31) >> 3)) * 16 + (o & 15)) * 8 + (k & 7);
      wt0hi[oi] = hb;
      wt0lo[oi] = bf16_rne(v - __uint_as_float((unsigned)hb << 16));
    }
    if (gtid < 65536) {  // W1: K=256 (KS=8)
      int head = gtid >> 14, idx = gtid & 16383;
      int o = idx >> 8, k = idx & 255;
      float v = gatW1[((size_t)head * 256 + k) * 64 + o];
      unsigned short hb = bf16_rne(v);
      size_t oi = (((((size_t)head * 4 + (o >> 4)) * 8 + (k >> 5)) * 4 + ((k & 31) >> 3)) * 16 + (o & 15)) * 8 + (k & 7);
      wt1hi[oi] = hb;
      wt1lo[oi] = bf16_rne(v - __uint_as_float((unsigned)hb << 16));
    }
  }
  if (b < 256) {  // encoder MLP, 8 nodes/block (two 4-node halves)
    __shared__ float nfs[2][4][10], x1e[2][4][64], pred[2][4][4][64];
    const int half = t >> 8, tl = t & 255;
    const int j = tl >> 6, o = tl & 63;
    const int n0 = b * 8 + half * 4;
    if (tl < 40) nfs[half][tl / 10][tl % 10] = nf[n0 * 10 + tl];
    __syncthreads();
    float acc = encb1[o];
#pragma unroll
    for (int k = 0; k < 10; k++) acc = fmaf(nfs[half][j][k], encW1[k * 64 + o], acc);
    x1e[half][j][o] = fmaxf(acc, 0.f);
    __syncthreads();
    {
      const int kq = j;
      float pp0 = 0, pp1 = 0, pp2 = 0, pp3 = 0;
#pragma unroll
      for (int kk = 0; kk < 16; kk++) {
        int k = kq * 16 + kk;
        float wv = encW2[k * 64 + o];
        pp0 = fmaf(x1e[half][0][k], wv, pp0);
        pp1 = fmaf(x1e[half][1][k], wv, pp1);
        pp2 = fmaf(x1e[half][2][k], wv, pp2);
        pp3 = fmaf(x1e[half][3][k], wv, pp3);
      }
      pred[half][kq][0][o] = pp0; pred[half][kq][1][o] = pp1;
      pred[half][kq][2][o] = pp2; pred[half][kq][3][o] = pp3;
    }
    __syncthreads();
    float v = encb2[o] + pred[half][0][j][o] + pred[half][1][j][o] +
              pred[half][2][j][o] + pred[half][3][j][o];
    const int n = n0 + j;  // node; feature k = o; K=64 -> KS=2
    size_t oi = ((((size_t)(n >> 4) * 2 + (o >> 5)) * 4 + ((o & 31) >> 3)) * 16 + (n & 15)) * 8 + (o & 7);
    x0hi[oi] = bf16_rne(v);
  }
}

// ---------------- MFMA projection (fragment-packed operands, 2-term hi/lo) ----------------
// grid (N/16, H), block 256 = 4 waves; wave = o-strip. Writes hTp + s1/s2 (log2e) + pm1.
template <int K>
__global__ void __launch_bounds__(256, 4)
proj_mfma_kernel(const unsigned short* __restrict__ xhi,
                 const unsigned short* __restrict__ wthi, const unsigned short* __restrict__ wtlo,
                 const float* __restrict__ avec,
                 unsigned short* __restrict__ hT, float* __restrict__ s1, float* __restrict__ s2,
                 float* __restrict__ pm1) {
  constexpr int KS = K / 32;
  const int head = blockIdx.y;
  const int n0 = blockIdx.x * 16;
  const int wave = threadIdx.x >> 6, lane = threadIdx.x & 63;
  const int il = lane & 15, kgrp = lane >> 4;
  const int o0 = wave * 16;
  const unsigned short* __restrict__ Ah = wthi + ((size_t)(head * 4 + wave) * KS) * 512 + lane * 8;
  const unsigned short* __restrict__ Al = wtlo + ((size_t)(head * 4 + wave) * KS) * 512 + lane * 8;
  const unsigned short* __restrict__ Bh = xhi + ((size_t)blockIdx.x * KS) * 512 + lane * 8;
  f32x4 acc = {0, 0, 0, 0};
#pragma unroll
  for (int ks = 0; ks < KS; ks++) {
    short8v ah = *(const short8v*)(Ah + ks * 512);
    short8v al = *(const short8v*)(Al + ks * 512);
    short8v bh = *(const short8v*)(Bh + ks * 512);
    acc = __builtin_amdgcn_mfma_f32_16x16x32_bf16(ah, bh, acc, 0, 0, 0);
    acc = __builtin_amdgcn_mfma_f32_16x16x32_bf16(al, bh, acc, 0, 0, 0);
  }
  // D: o = o0 + kgrp*4 + r (row), n = n0 + il (col). Write hTp layout.
  const int n = n0 + il;
  const size_t cbase = (((size_t)head * (N / 32) + (n >> 5)) * 4 + wave) * 512;
  const int sub = ((n & 31) >> 3) * 16;  // kgrp_agg*16
  const int eoff = n & 7;
  float p1 = 0.f, p2 = 0.f;
#pragma unroll
  for (int r = 0; r < 4; r++) {
    const int o = o0 + kgrp * 4 + r;
    hT[cbase + (size_t)(sub + kgrp * 4 + r) * 8 + eoff] = bf16_rne(acc[r]);
    p1 = fmaf(acc[r], avec[head * 128 + o], p1);
    p2 = fmaf(acc[r], avec[head * 128 + 64 + o], p2);
  }
  p1 += __shfl_xor(p1, 16); p1 += __shfl_xor(p1, 32);
  p2 += __shfl_xor(p2, 16); p2 += __shfl_xor(p2, 32);
  __shared__ float s1p[4][16], s2p[4][16];
  if (kgrp == 0) { s1p[wave][il] = p1; s2p[wave][il] = p2; }
  __syncthreads();
  if (threadIdx.x < 16) {
    int nn = n0 + threadIdx.x;
    float v1 = (s1p[0][threadIdx.x] + s1p[1][threadIdx.x] + s1p[2][threadIdx.x] + s1p[3][threadIdx.x]) * LOG2E;
    float v2 = (s2p[0][threadIdx.x] + s2p[1][threadIdx.x] + s2p[2][threadIdx.x] + s2p[3][threadIdx.x]) * LOG2E;
    s1[head * N + nn] = v1;
    s2[head * N + nn] = v2;
    float m1 = v1;
#pragma unroll
    for (int s = 1; s < 16; s <<= 1) m1 = fmaxf(m1, __shfl_xor(m1, s));
    if (threadIdx.x == 0) pm1[head * 128 + blockIdx.x] = m1;
  }
}

// ---------------- fused MFMA aggregation + denom + normalize + ELU + concat ----------------
// grid (N/16, H), block 512 = 8 waves; wave w = K-chunk of 256 q. Single-MFMA, packed B.
// VALU-trimmed: lrelu-sub fold (c1/c2) + v_cvt_pk_bf16_f32 packing.
template <bool WF32, bool WBF>
__global__ void __launch_bounds__(512, 4)
agg_fused_kernel(const unsigned short* __restrict__ hTu,
                 const float* __restrict__ s1, const float* __restrict__ s2,
                 const float* __restrict__ pm1,
                 const unsigned long long* __restrict__ mask,
                 float* __restrict__ xout, unsigned short* __restrict__ xohi) {
  const int head = blockIdx.y;
  const int p0 = blockIdx.x * 16;
  const int wave = threadIdx.x >> 6, lane = threadIdx.x & 63;
  const int col = lane & 15, kgrp = lane >> 4;
  const int p = p0 + col;
  const float s2pv = s2[head * N + p];
  float sm = fmaxf(pm1[head * 128 + lane], pm1[head * 128 + 64 + lane]);
#pragma unroll
  for (int s = 1; s < 64; s <<= 1) sm = fmaxf(sm, __shfl_xor(sm, s));
  const float mraw = sm + s2pv;
  const float mp = fmaxf(mraw, ALPHA * mraw);
  // fold: lrelu(sv+s2p) - mp = max(sv + c1, ALPHA*sv + c2)
  const float c1 = s2pv - mp;
  const float c2 = ALPHA * s2pv - mp;
  const float* __restrict__ s1h = s1 + head * N;
  const int qbase = wave * 256;
  const unsigned long long* __restrict__ mr = mask + (size_t)p * NW + (qbase >> 6);
  unsigned long long mw0 = mr[0], mw1 = mr[1], mw2 = mr[2], mw3 = mr[3];
  const unsigned short* __restrict__ bbase =
      hTu + (((size_t)head * (N / 32) + wave * 8) * 4) * 512 + lane * 8;

  f32x4 acc[4] = {{0,0,0,0},{0,0,0,0},{0,0,0,0},{0,0,0,0}};
  float wsum = 0.f;
#pragma unroll
  for (int ks = 0; ks < 8; ks++) {
    const int qa = qbase + ks * 32 + kgrp * 8;
    float4 s1v0 = *(const float4*)(s1h + qa);
    float4 s1v1 = *(const float4*)(s1h + qa + 4);
    unsigned long long mwsel = (ks < 2) ? mw0 : (ks < 4) ? mw1 : (ks < 6) ? mw2 : mw3;
    unsigned b8 = (unsigned)((mwsel >> ((ks & 1) * 32 + kgrp * 8)) & 0xFFull);
    float sv[8] = {s1v0.x, s1v0.y, s1v0.z, s1v0.w, s1v1.x, s1v1.y, s1v1.z, s1v1.w};
    float w[8];
#pragma unroll
    for (int e = 0; e < 8; e++) {
      float lr = fmaxf(sv[e] + c1, fmaf(sv[e], ALPHA, c2));
      float ww = exp2f(lr);
      ww = ((b8 >> e) & 1u) ? ww : 0.f;
      wsum += ww;
      w[e] = ww;
    }
    union { short8v s; unsigned u[4]; } av;
#pragma unroll
    for (int e2 = 0; e2 < 4; e2++)
      asm("v_cvt_pk_bf16_f32 %0, %1, %2" : "=v"(av.u[e2]) : "v"(w[2 * e2]), "v"(w[2 * e2 + 1]));
#pragma unroll
    for (int ff = 0; ff < 4; ff++) {
      short8v b_hi = *(const short8v*)(bbase + ((size_t)ks * 4 + ff) * 512);
      acc[ff] = __builtin_amdgcn_mfma_f32_16x16x32_bf16(av.s, b_hi, acc[ff], 0, 0, 0);
    }
  }
  wsum += __shfl_xor(wsum, 16);
  wsum += __shfl_xor(wsum, 32);

  __shared__ float red[8][16][65];
  __shared__ float wred[8][16];
#pragma unroll
  for (int ff = 0; ff < 4; ff++)
#pragma unroll
    for (int r = 0; r < 4; r++)
      red[wave][kgrp * 4 + r][ff * 16 + col] = acc[ff][r];
  if (lane < 16) wred[wave][lane] = wsum;
  __syncthreads();
#pragma unroll
  for (int rep = 0; rep < 2; rep++) {
    int idx = threadIdx.x + rep * 512;
    int pl = idx >> 6, f = idx & 63;
    float num = 0.f, dn = 0.f;
#pragma unroll
    for (int w8 = 0; w8 < 8; w8++) { num += red[w8][pl][f]; dn += wred[w8][pl]; }
    float v = num / dn;
    v = v > 0.f ? v : (__expf(v) - 1.f);
    if (WF32) xout[(size_t)(p0 + pl) * 256 + head * 64 + f] = v;
    if (WBF) {
      // xp layout for proj<256>: node nn=p0+pl (tile=blockIdx.x), feature k=head*64+f
      size_t oi = ((((size_t)blockIdx.x * 8 + head * 2 + (f >> 5)) * 4 + ((f & 31) >> 3)) * 16 + pl) * 8 + (f & 7);
      xohi[oi] = bf16_rne(v);
    }
  }
}

// ---------------- layer-2 projection (F_out=3), 4 nodes/block, h2 stride-4 ----------------
__global__ void h3_kernel(const float* __restrict__ x, const float* __restrict__ W,
                          const float* __restrict__ a, float* __restrict__ h2,
                          float* __restrict__ s1, float* __restrict__ s2,
                          float* __restrict__ pm1h3) {
  const int n0 = blockIdx.x * 4;
  const int head = threadIdx.x >> 6, o = threadIdx.x & 63;
  __shared__ float xr[4][256];
  for (int k = threadIdx.x; k < 1024; k += 256) xr[k >> 8][k & 255] = x[(size_t)n0 * 256 + k];
  __syncthreads();
  const float* __restrict__ Wh = W + (size_t)head * 256 * 3;
  float m1 = -3.4e38f;
#pragma unroll
  for (int jj = 0; jj < 4; jj++) {
    float a0 = 0.f, a1 = 0.f, a2 = 0.f;
#pragma unroll
    for (int i = 0; i < 4; i++) {
      int k = o + 64 * i;
      float xv = xr[jj][k];
      a0 = fmaf(xv, Wh[k * 3 + 0], a0);
      a1 = fmaf(xv, Wh[k * 3 + 1], a1);
      a2 = fmaf(xv, Wh[k * 3 + 2], a2);
    }
    for (int s = 32; s; s >>= 1) {
      a0 += __shfl_xor(a0, s); a1 += __shfl_xor(a1, s); a2 += __shfl_xor(a2, s);
    }
    float p1 = (a0 * a[head * 6 + 0] + a1 * a[head * 6 + 1] + a2 * a[head * 6 + 2]) * LOG2E;
    float p2 = (a0 * a[head * 6 + 3] + a1 * a[head * 6 + 4] + a2 * a[head * 6 + 5]) * LOG2E;
    m1 = fmaxf(m1, p1);
    if (o == 0) {
      float* hq = h2 + ((size_t)head * N + n0 + jj) * 4;
      hq[0] = a0; hq[1] = a1; hq[2] = a2; hq[3] = 0.f;
      s1[head * N + n0 + jj] = p1;
      s2[head * N + n0 + jj] = p2;
    }
  }
  if (o == 0) pm1h3[head * 512 + blockIdx.x] = m1;
}

// ---------------- layer-2 aggregation, self-normalizing, fused head-mean + ELU -> emb ----------------
__global__ void agg2_kernel(const float* __restrict__ h2, const float* __restrict__ s1,
                            const float* __restrict__ s2, const float* __restrict__ pm1h3,
                            const unsigned long long* __restrict__ mask,
                            float* __restrict__ emb) {
  const int p = blockIdx.x;
  const int head = threadIdx.x >> 6, lane = threadIdx.x & 63;
  const float s2pv = s2[head * N + p];
  float sm = -3.4e38f;
  for (int i = lane; i < 512; i += 64) sm = fmaxf(sm, pm1h3[head * 512 + i]);
#pragma unroll
  for (int s = 1; s < 64; s <<= 1) sm = fmaxf(sm, __shfl_xor(sm, s));
  float mraw = sm + s2pv;
  const float mhv = fmaxf(mraw, ALPHA * mraw);
  const float c1 = s2pv - mhv;
  const float c2 = ALPHA * s2pv - mhv;
  const float* __restrict__ s1h = s1 + head * N;
  float a0 = 0.f, a1 = 0.f, a2 = 0.f, wsum = 0.f;
#pragma unroll 2
  for (int i = 0; i < 32; i++) {
    unsigned long long mwd = mask[(size_t)p * NW + i];
    int q = i * 64 + lane;
    if ((mwd >> lane) & 1ull) {
      float sv = s1h[q];
      float lr = fmaxf(sv + c1, fmaf(sv, ALPHA, c2));
      float w = exp2f(lr);
      float4 hv = *(const float4*)(h2 + ((size_t)head * N + q) * 4);
      a0 = fmaf(w, hv.x, a0);
      a1 = fmaf(w, hv.y, a1);
      a2 = fmaf(w, hv.z, a2);
      wsum += w;
    }
  }
  for (int s = 32; s; s >>= 1) {
    a0 += __shfl_xor(a0, s); a1 += __shfl_xor(a1, s);
    a2 += __shfl_xor(a2, s); wsum += __shfl_xor(wsum, s);
  }
  __shared__ float red[4][4];
  if (lane == 0) { red[head][0] = a0; red[head][1] = a1; red[head][2] = a2; red[head][3] = wsum; }
  __syncthreads();
  if (threadIdx.x < 3) {
    int f = threadIdx.x;
    float v = 0.f;
#pragma unroll
    for (int hh = 0; hh < 4; hh++) v += red[hh][f] / red[hh][3];
    v *= 0.25f;
    v = v > 0.f ? v : (__expf(v) - 1.f);
    emb[p * 3 + f] = v;
  }
}

// ---------------- all-pairs edge classifier (packed fp16 inner) ----------------
__global__ void cls_kernel(const float* __restrict__ emb,
                           const float* __restrict__ W1, const float* __restrict__ b1,
                           const float* __restrict__ W2, const float* __restrict__ b2,
                           float* __restrict__ out) {
  int q = blockIdx.x * 256 + threadIdx.x;
  int p0 = blockIdx.y * 8;
  __shared__ float ep[8][3];
  __shared__ __half2 w1h[96], b1h[32], w2h[32];
  __shared__ float b2s;
  int t = threadIdx.x;
  if (t < 96) w1h[t] = __float2half2_rn(W1[t]);
  else if (t < 128) b1h[t - 96] = __float2half2_rn(b1[t - 96]);
  else if (t < 160) w2h[t - 128] = __float2half2_rn(W2[t - 128]);
  else if (t == 160) b2s = b2[0];
  else if (t >= 192 && t < 216) ((float*)ep)[t - 192] = emb[p0 * 3 + t - 192];
  __syncthreads();
  float e0 = emb[q * 3 + 0], e1 = emb[q * 3 + 1], e2 = emb[q * 3 + 2];
  __half2 d0[4], d1[4], d2[4];
#pragma unroll
  for (int ip = 0; ip < 4; ip++) {
    d0[ip] = __floats2half2_rn(fabsf(ep[2 * ip][0] - e0), fabsf(ep[2 * ip + 1][0] - e0));
    d1[ip] = __floats2half2_rn(fabsf(ep[2 * ip][1] - e1), fabsf(ep[2 * ip + 1][1] - e1));
    d2[ip] = __floats2half2_rn(fabsf(ep[2 * ip][2] - e2), fabsf(ep[2 * ip + 1][2] - e2));
  }
  const __half2 hz = __float2half2_rn(0.f);
  __half2 acc[4] = {hz, hz, hz, hz};
#pragma unroll
  for (int j = 0; j < 32; j++) {
    __half2 c0 = w1h[j], c1 = w1h[32 + j], c2 = w1h[64 + j], bb = b1h[j], w2 = w2h[j];
#pragma unroll
    for (int ip = 0; ip < 4; ip++) {
      __half2 hv = __hfma2(d0[ip], c0, __hfma2(d1[ip], c1, __hfma2(d2[ip], c2, bb)));
      hv = relu_h2(hv);
      acc[ip] = __hfma2(hv, w2, acc[ip]);
    }
  }
#pragma unroll
  for (int ip = 0; ip < 4; ip++) {
    float x0 = __low2float(acc[ip]) + b2s;
    float x1 = __high2float(acc[ip]) + b2s;
    out[(size_t)(p0 + 2 * ip) * N + q] = 1.f / (1.f + __expf(-x0));
    out[(size_t)(p0 + 2 * ip + 1) * N + q] = 1.f / (1.f + __expf(-x1));
  }
}

extern "C" void kernel_launch(void* const* d_in, const int* in_sizes, int n_in,
                              void* d_out, int out_size, void* d_ws, size_t ws_size,
                              hipStream_t stream) {
  const float* nf    = (const float*)d_in[0];
  const int*   adj   = (const int*)d_in[1];
  const float* encW1 = (const float*)d_in[2];
  const float* encb1 = (const float*)d_in[3];
  const float* encW2 = (const float*)d_in[4];
  const float* encb2 = (const float*)d_in[5];
  const float* gatW0 = (const float*)d_in[6];
  const float* gata0 = (const float*)d_in[7];
  const float* gatW1 = (const float*)d_in[8];
  const float* gata1 = (const float*)d_in[9];
  const float* gatW2 = (const float*)d_in[10];
  const float* gata2 = (const float*)d_in[11];
  const float* clsW1 = (const float*)d_in[12];
  const float* clsb1 = (const float*)d_in[13];
  const float* clsW2 = (const float*)d_in[14];
  const float* clsb2 = (const float*)d_in[15];

  float* ws = (float*)d_ws;
  unsigned short* hT   = (unsigned short*)ws;              // 524288 sh = 262144 f
  float* s1   = ws + 262144;                               // 8192
  float* s2   = s1 + 8192;                                 // 8192
  float* pm1  = s2 + 8192;                                 // 512
  float* pm1h3= pm1 + 512;                                 // 2048
  unsigned short* x0hi = (unsigned short*)(pm1h3 + 2048);  // 65536 f
  unsigned short* wt0hi= x0hi + 131072;                    // 8192 f
  unsigned short* wt0lo= wt0hi + 16384;                    // 8192 f
  unsigned short* wt1hi= wt0lo + 16384;                    // 32768 f
  unsigned short* wt1lo= wt1hi + 65536;                    // 32768 f
  unsigned short* xAhi = wt1lo + 65536;                    // 262144 f
  float* xB   = (float*)(xAhi + 524288);                   // 524288 f
  float* h2   = xB + 524288;                               // 32768 f (stride-4)
  unsigned long long* mask = (unsigned long long*)(h2 + 32768); // 131072 f

  float* emb = (float*)d_out;
  float* eprob = emb + N * 3;

  prep_kernel<<<dim3(512), dim3(512), 0, stream>>>(
      nf, adj, encW1, encb1, encW2, encb2, gatW0, gatW1,
      mask, wt0hi, wt0lo, wt1hi, wt1lo, x0hi);

  // ---- GAT layer 0 ----
  proj_mfma_kernel<64><<<dim3(N / 16, 4), dim3(256), 0, stream>>>(
      x0hi, wt0hi, wt0lo, gata0, hT, s1, s2, pm1);
  agg_fused_kernel<false, true><<<dim3(N / 16, 4), dim3(512), 0, stream>>>(
      hT, s1, s2, pm1, mask, nullptr, xAhi);

  // ---- GAT layer 1 ----
  proj_mfma_kernel<256><<<dim3(N / 16, 4), dim3(256), 0, stream>>>(
      xAhi, wt1hi, wt1lo, gata1, hT, s1, s2, pm1);
  agg_fused_kernel<true, false><<<dim3(N / 16, 4), dim3(512), 0, stream>>>(
      hT, s1, s2, pm1, mask, xB, nullptr);

  // ---- GAT layer 2 ----
  h3_kernel<<<dim3(N / 4), dim3(256), 0, stream>>>(xB, gatW2, gata2, h2, s1, s2, pm1h3);
  agg2_kernel<<<dim3(N), dim3(256), 0, stream>>>(h2, s1, s2, pm1h3, mask, emb);

  // ---- classifier ----
  cls_kernel<<<dim3(8, N / 8), dim3(256), 0, stream>>>(emb, clsW1, clsb1, clsW2, clsb2, eprob);
}